// Round 9
// baseline (228.460 us; speedup 1.0000x reference)
//
#include <hip/hip_runtime.h>
#include <hip/hip_bf16.h>

// Problem constants
#define LNUM 8
#define ENUM 8
#define DDIM 256
#define BSZ  16384
#define H1N  64
#define H2N  32

#define BT   32     // rows per block  (grid 512 -> 2 blocks/CU)
#define NTHR 512    // 8 waves: one expert per wave -> 4 waves/SIMD

// LDS pitches (u16 elements); odd 16B-granule strides -> conflict-light
#define PX   264    // x tile (D + 8)
#define PH1  72     // h1 tile pitch (H1 + 8)   [row][feat]
#define PH2  40     // h2 tile pitch (H2 + 8)   [row][feat]
#define PSW  9      // softmax weights pitch (floats)

// ws element offsets (u16 elems) for fragment-ordered weights
#define WS1_OFF 0           // 64 steps * 16384 elems
#define WS2_OFF 1048576     // 64 steps * 2048
#define WS3_OFF 1179648     // 64 steps * 8192

typedef float f32x4 __attribute__((ext_vector_type(4)));
typedef unsigned short u16x8 __attribute__((ext_vector_type(8)));
typedef unsigned short u16x4 __attribute__((ext_vector_type(4)));
typedef __bf16 bf16x8 __attribute__((ext_vector_type(8)));

#define Z4 ((f32x4){0.f, 0.f, 0.f, 0.f})

// f32 -> bf16 RTNE via native cast (compiler pairs into v_cvt_pk_bf16_f32).
static __device__ __forceinline__ unsigned short f2bf(float f) {
    __bf16 h = (__bf16)f;
    return __builtin_bit_cast(unsigned short, h);
}

// D[m][n] = sum_k A[m][k]*B[n][k] + C : A supplies m, B supplies n, frags are
// symmetric [idx16][K] -> swapping args transposes the output tile.
static __device__ __forceinline__ f32x4 mfma16(u16x8 a, u16x8 b, f32x4 c) {
    return __builtin_amdgcn_mfma_f32_16x16x32_bf16(
        __builtin_bit_cast(bf16x8, a), __builtin_bit_cast(bf16x8, b), c, 0, 0, 0);
}

// Barrier with lgkmcnt-only drain: LDS producer/consumer ordering preserved,
// in-flight GLOBAL loads are NOT drained (vs __syncthreads' vmcnt(0)).
// Safe: all inter-wave data flows through LDS; no global stores in the loop.
// HW-validated rounds 2/4/5/6/7/8.
static __device__ __forceinline__ void lbar() {
    asm volatile("s_waitcnt lgkmcnt(0)" ::: "memory");
    __builtin_amdgcn_s_barrier();
    asm volatile("" ::: "memory");
}

// ---------------------------------------------------------------------------
// Kernel 1: fp32 weights -> bf16 B-fragment layout. Unchanged.
// Fragment: 64 lanes x 8 elems; slot (q*16+r) holds W[n0+r][k0+q*8 .. +7].
// ---------------------------------------------------------------------------
__global__ __launch_bounds__(256) void cvt_w_frag(
    const float* __restrict__ w1, const float* __restrict__ w2,
    const float* __restrict__ w3, unsigned short* __restrict__ ws)
{
    int gid = blockIdx.x * 256 + threadIdx.x;
    const float* src;
    unsigned short* dst;
    if (gid < 131072) {                          // W1: [s][n(64)][k(256)]
        int s = gid >> 11, rem = gid & 2047;
        int n = rem >> 5, kc = rem & 31;
        int nt = n >> 4, r = n & 15, kt = kc >> 2, q = kc & 3;
        src = w1 + (size_t)gid * 8;
        dst = ws + WS1_OFF + (size_t)s * 16384 + nt * 4096 + kt * 512 + (q * 16 + r) * 8;
    } else if (gid < 147456) {                   // W2: [s][n(32)][k(64)]
        int g = gid - 131072;
        int s = g >> 8, rem = g & 255;
        int n = rem >> 3, kc = rem & 7;
        int n2 = n >> 4, r = n & 15, kt = kc >> 2, q = kc & 3;
        src = w2 + (size_t)g * 8;
        dst = ws + WS2_OFF + (size_t)s * 2048 + n2 * 1024 + kt * 512 + (q * 16 + r) * 8;
    } else {                                     // W3: [s][n(256)][k(32)]
        int g = gid - 147456;
        int s = g >> 10, rem = g & 1023;
        int n = rem >> 2, q = rem & 3;
        int nt = n >> 4, r = n & 15;
        src = w3 + (size_t)g * 8;
        dst = ws + WS3_OFF + (size_t)s * 8192 + nt * 512 + (q * 16 + r) * 8;
    }
    float4 a = *(const float4*)src;
    float4 b = *(const float4*)(src + 4);
    u16x8 p;
    p[0] = f2bf(a.x); p[1] = f2bf(a.y); p[2] = f2bf(a.z); p[3] = f2bf(a.w);
    p[4] = f2bf(b.x); p[5] = f2bf(b.y); p[6] = f2bf(b.z); p[7] = f2bf(b.w);
    *(u16x8*)dst = p;
}

// ---------------------------------------------------------------------------
// Kernel 2: fused 8-layer x 8-expert MoE MLP — one expert per wave, 8 waves.
// R8's structure with the pe-loop unrolled ACROSS waves: wave wv owns expert
// wv end-to-end through G1 (64 straight-line MFMA, wave-private H1W region)
// and G2 (8 MFMA); ONE barrier; G3 fans in all 8 experts with ACC split by
// (row-half rh=wv>>2, col-group cg=wv&3). Per-wave instruction texture is
// identical to R8; persistent state SHRINKS (ACC 32->16 regs) while waves/CU
// doubles to 16 (4/SIMD) at unchanged grid and L2 traffic -> 2x TLP to hide
// the L2 weight-load latency that R8 left exposed. 3 barriers/layer.
// ---------------------------------------------------------------------------
__global__ __launch_bounds__(NTHR, 4) void moe_fused(
    const float* __restrict__ src, const unsigned short* __restrict__ Wf,
    const float* __restrict__ b1, const float* __restrict__ b2,
    const float* __restrict__ b3, const float* __restrict__ masks,
    float* __restrict__ out)
{
    __shared__ __align__(16) unsigned short Xlds[BT * PX];        // 16896 B
    __shared__ __align__(16) unsigned short H1W[8][BT * PH1];     // 36864 B wave-private
    __shared__ __align__(16) unsigned short H2T[8][BT * PH2];     // 20480 B per-expert
    __shared__ float SWlds[BT * PSW];                             //  1152 B
    // total 75392 B -> 2 blocks/CU (150784 <= 160K)

    const int tid  = threadIdx.x;
    const int lane = tid & 63;
    const int wv   = tid >> 6;      // wave id 0..7: expert (G1/G2)
    const int rh   = wv >> 2;       // G3 row-half
    const int cg   = wv & 3;        // G3 col-group
    const int n15  = lane & 15;
    const int q    = lane >> 4;
    const int b0   = blockIdx.x * BT;

    const unsigned short* w3base = Wf + WS3_OFF + cg * 2048 + lane * 8;

    u16x8 xf[2][8];          // persistent x B-frags (dead during G3)
    f32x4 ACC[4];            // 16-row x 64-col accumulator (dead during G1/G2)

    auto stage_softmax = [&](int l) {
        if (tid < BT) {
            const float* mp = masks + ((size_t)l * BSZ + b0 + tid) * ENUM;
            float4 m0 = *(const float4*)mp;
            float4 m1 = *(const float4*)(mp + 4);
            float mv[8] = {m0.x, m0.y, m0.z, m0.w, m1.x, m1.y, m1.z, m1.w};
            float mx = mv[0];
            #pragma unroll
            for (int e = 1; e < 8; ++e) mx = fmaxf(mx, mv[e]);
            float s = 0.f;
            #pragma unroll
            for (int e = 0; e < 8; ++e) { mv[e] = expf(mv[e] - mx); s += mv[e]; }
            float inv = 1.f / s;
            #pragma unroll
            for (int e = 0; e < 8; ++e) SWlds[tid * PSW + e] = mv[e] * inv;
        }
    };

    // ACC = sum_e softmax_w[row][e] * b3[e][col]  (fp32 VALU, once per layer)
    auto acc_init = [&](int l) {
        const float* b3l = b3 + (size_t)l * ENUM * DDIM;
        #pragma unroll
        for (int nt = 0; nt < 4; ++nt) ACC[nt] = Z4;
        #pragma unroll 2
        for (int e2 = 0; e2 < ENUM; ++e2) {
            float swv[4];
            #pragma unroll
            for (int rr = 0; rr < 4; ++rr)
                swv[rr] = SWlds[(rh*16 + q*4 + rr) * PSW + e2];
            #pragma unroll
            for (int nt = 0; nt < 4; ++nt) {
                float bv = b3l[e2 * DDIM + cg*64 + nt*16 + n15];
                #pragma unroll
                for (int rr = 0; rr < 4; ++rr)
                    ACC[nt][rr] += swv[rr] * bv;
            }
        }
    };

    auto xf_read = [&]() {
        #pragma unroll
        for (int mt = 0; mt < 2; ++mt)
            #pragma unroll
            for (int kt = 0; kt < 8; ++kt)
                xf[mt][kt] = *(const u16x8*)
                    &Xlds[(mt*16 + n15) * PX + q*8 + kt*32];
    };
    auto x_write = [&]() {
        #pragma unroll
        for (int nt = 0; nt < 4; ++nt)
            #pragma unroll
            for (int rr = 0; rr < 4; ++rr)
                Xlds[(rh*16 + q*4 + rr) * PX + cg*64 + nt*16 + n15] =
                    f2bf(ACC[nt][rr]);
    };

    // ================= prologue =================
    #pragma unroll
    for (int i = 0; i < 2; ++i) {                // stage layer-0 x (bf16)
        int o = (i * NTHR + tid) * 8;
        int r = o >> 8, c = o & 255;
        const float* p = src + (size_t)(b0 + r) * DDIM + c;
        float4 f0 = *(const float4*)(p);
        float4 f1 = *(const float4*)(p + 4);
        u16x8 pk;
        pk[0] = f2bf(f0.x); pk[1] = f2bf(f0.y); pk[2] = f2bf(f0.z); pk[3] = f2bf(f0.w);
        pk[4] = f2bf(f1.x); pk[5] = f2bf(f1.y); pk[6] = f2bf(f1.z); pk[7] = f2bf(f1.w);
        *(u16x8*)&Xlds[r * PX + c] = pk;
    }
    stage_softmax(0);
    __syncthreads();
    xf_read();

    // ================= layer loop =================
    #pragma unroll 1
    for (int l = 0; l < LNUM; ++l) {
        const int sbase = l * ENUM;
        const int s = sbase + wv;        // this wave's expert step

        // ===== G1: h1 = relu(x @ W1^T + b1), 4 feat-tiles (barrier-free) =====
        // lane -> feats ft*16+q*4+rr, rows mt*16+n15 (transposed MFMA)
        #pragma unroll
        for (int ft = 0; ft < 4; ++ft) {
            u16x8 w1f[8];
            const unsigned short* p1 =
                Wf + WS1_OFF + (size_t)s * 16384 + ft * 4096 + lane * 8;
            #pragma unroll
            for (int kt = 0; kt < 8; ++kt)
                w1f[kt] = *(const u16x8*)(p1 + kt * 512);
            f32x4 a1[2] = {Z4, Z4};
            #pragma unroll
            for (int kt = 0; kt < 8; ++kt) {
                a1[0] = mfma16(w1f[kt], xf[0][kt], a1[0]);
                a1[1] = mfma16(w1f[kt], xf[1][kt], a1[1]);
            }
            const float4 bb1 = *(const float4*)(b1 + s * 64 + ft * 16 + q * 4);
            #pragma unroll
            for (int mt = 0; mt < 2; ++mt) {
                u16x4 pk;
                #pragma unroll
                for (int rr = 0; rr < 4; ++rr)
                    pk[rr] = f2bf(fmaxf(a1[mt][rr] + bb1[rr], 0.f));
                *(u16x4*)&H1W[wv][(mt*16 + n15) * PH1 + ft*16 + q*4] = pk;
            }
        }

        // ===== G2: h2 = relu(h1 @ W2^T + b2) * sw[wv] (intra-wave, no bar) =====
        {
            u16x8 w2f[2][2];
            const unsigned short* p2 = Wf + WS2_OFF + (size_t)s * 2048 + lane * 8;
            #pragma unroll
            for (int f2 = 0; f2 < 2; ++f2)
                #pragma unroll
                for (int kt = 0; kt < 2; ++kt)
                    w2f[f2][kt] = *(const u16x8*)(p2 + f2*1024 + kt*512);
            u16x8 h1f[2][2];
            #pragma unroll
            for (int mt = 0; mt < 2; ++mt)
                #pragma unroll
                for (int kt = 0; kt < 2; ++kt)
                    h1f[mt][kt] = *(const u16x8*)
                        &H1W[wv][(mt*16 + n15) * PH1 + q*8 + kt*32];
            f32x4 a2[2][2] = {{Z4, Z4}, {Z4, Z4}};
            #pragma unroll
            for (int f2 = 0; f2 < 2; ++f2)
                #pragma unroll
                for (int mt = 0; mt < 2; ++mt)
                    #pragma unroll
                    for (int kt = 0; kt < 2; ++kt)
                        a2[f2][mt] = mfma16(w2f[f2][kt], h1f[mt][kt], a2[f2][mt]);
            float swv[2];
            #pragma unroll
            for (int mt = 0; mt < 2; ++mt)
                swv[mt] = SWlds[(mt*16 + n15) * PSW + wv];
            #pragma unroll
            for (int f2 = 0; f2 < 2; ++f2) {
                const float4 bb2 = *(const float4*)(b2 + s * 32 + f2 * 16 + q * 4);
                #pragma unroll
                for (int mt = 0; mt < 2; ++mt) {
                    u16x4 pk;
                    #pragma unroll
                    for (int rr = 0; rr < 4; ++rr)
                        pk[rr] = f2bf(fmaxf(a2[f2][mt][rr] + bb2[rr], 0.f) * swv[mt]);
                    *(u16x4*)&H2T[wv][(mt*16 + n15) * PH2 + f2*16 + q*4] = pk;
                }
            }
        }

        lbar();                     // all 8 experts' h2 ready (only mid-layer barrier)

        // ===== ACC init (deferred: ACC dead during G1/G2) =====
        acc_init(l);

        // ===== G3: all 8 experts, rows rh*16..+15, cols cg*64..+63 =====
        #pragma unroll
        for (int e = 0; e < ENUM; ++e) {
            u16x8 w3f[4];
            const unsigned short* p3 = w3base + (size_t)(sbase + e) * 8192;
            #pragma unroll
            for (int nt = 0; nt < 4; ++nt)
                w3f[nt] = *(const u16x8*)(p3 + nt * 512);
            u16x8 h = *(const u16x8*)&H2T[e][(rh*16 + n15) * PH2 + q*8];
            #pragma unroll
            for (int nt = 0; nt < 4; ++nt)
                ACC[nt] = mfma16(h, w3f[nt], ACC[nt]);
        }

        // ===== layer transition =====
        if (l < LNUM - 1) {
            x_write();
            lbar();
            xf_read();
            stage_softmax(l + 1);
            lbar();
        }
    }

    // ================= final store (fp32) =================
    #pragma unroll
    for (int nt = 0; nt < 4; ++nt)
        #pragma unroll
        for (int rr = 0; rr < 4; ++rr)
            out[(size_t)(b0 + rh*16 + q*4 + rr) * DDIM
                + cg*64 + nt*16 + n15] = ACC[nt][rr];
}

extern "C" void kernel_launch(void* const* d_in, const int* in_sizes, int n_in,
                              void* d_out, int out_size, void* d_ws, size_t ws_size,
                              hipStream_t stream) {
    const float* src   = (const float*)d_in[0];
    const float* W1    = (const float*)d_in[1];
    const float* b1    = (const float*)d_in[2];
    const float* W2    = (const float*)d_in[3];
    const float* b2    = (const float*)d_in[4];
    const float* W3    = (const float*)d_in[5];
    const float* b3    = (const float*)d_in[6];
    const float* masks = (const float*)d_in[7];
    float* out = (float*)d_out;
    unsigned short* ws = (unsigned short*)d_ws;   // needs 3,407,872 B

    hipLaunchKernelGGL(cvt_w_frag, dim3(832), dim3(256), 0, stream, W1, W2, W3, ws);
    hipLaunchKernelGGL(moe_fused, dim3(BSZ / BT), dim3(NTHR), 0, stream,
                       src, ws, b1, b2, b3, masks, out);
}

// Round 10
// 228.358 us; speedup vs baseline: 1.0004x; 1.0004x over previous
//
#include <hip/hip_runtime.h>
#include <hip/hip_bf16.h>

// Problem constants
#define LNUM 8
#define ENUM 8
#define DDIM 256
#define BSZ  16384
#define H1N  64
#define H2N  32

#define BT   32     // rows per block  (grid 512 -> 2 blocks/CU, LDS-capped)
#define NTHR 512    // 8 waves: one expert per wave -> 4 waves/SIMD

// LDS pitches (u16 elements); odd 16B-granule strides -> conflict-light
#define PX   264    // x tile (D + 8)
#define PH1  72     // h1 tile pitch (H1 + 8)   [row][feat]
#define PH2  40     // h2 tile pitch (H2 + 8)   [row][feat]
#define PSW  9      // softmax weights pitch (floats)

// ws element offsets (u16 elems) for fragment-ordered weights
#define WS1_OFF 0           // 64 steps * 16384 elems
#define WS2_OFF 1048576     // 64 steps * 2048
#define WS3_OFF 1179648     // 64 steps * 8192

typedef float f32x4 __attribute__((ext_vector_type(4)));
typedef unsigned short u16x8 __attribute__((ext_vector_type(8)));
typedef unsigned short u16x4 __attribute__((ext_vector_type(4)));
typedef __bf16 bf16x8 __attribute__((ext_vector_type(8)));

#define Z4 ((f32x4){0.f, 0.f, 0.f, 0.f})

// f32 -> bf16 RTNE via native cast (compiler pairs into v_cvt_pk_bf16_f32).
static __device__ __forceinline__ unsigned short f2bf(float f) {
    __bf16 h = (__bf16)f;
    return __builtin_bit_cast(unsigned short, h);
}

// D[m][n] = sum_k A[m][k]*B[n][k] + C : A supplies m, B supplies n, frags are
// symmetric [idx16][K] -> swapping args transposes the output tile.
static __device__ __forceinline__ f32x4 mfma16(u16x8 a, u16x8 b, f32x4 c) {
    return __builtin_amdgcn_mfma_f32_16x16x32_bf16(
        __builtin_bit_cast(bf16x8, a), __builtin_bit_cast(bf16x8, b), c, 0, 0, 0);
}

// Barrier with lgkmcnt-only drain: LDS producer/consumer ordering preserved,
// in-flight GLOBAL loads are NOT drained (vs __syncthreads' vmcnt(0)).
// Safe: all inter-wave data flows through LDS; no global stores in the loop.
// HW-validated rounds 2/4/5/6/7/8/9.
static __device__ __forceinline__ void lbar() {
    asm volatile("s_waitcnt lgkmcnt(0)" ::: "memory");
    __builtin_amdgcn_s_barrier();
    asm volatile("" ::: "memory");
}

// ---------------------------------------------------------------------------
// Kernel 1: fp32 weights -> bf16 B-fragment layout. Unchanged.
// Fragment: 64 lanes x 8 elems; slot (q*16+r) holds W[n0+r][k0+q*8 .. +7].
// ---------------------------------------------------------------------------
__global__ __launch_bounds__(256) void cvt_w_frag(
    const float* __restrict__ w1, const float* __restrict__ w2,
    const float* __restrict__ w3, unsigned short* __restrict__ ws)
{
    int gid = blockIdx.x * 256 + threadIdx.x;
    const float* src;
    unsigned short* dst;
    if (gid < 131072) {                          // W1: [s][n(64)][k(256)]
        int s = gid >> 11, rem = gid & 2047;
        int n = rem >> 5, kc = rem & 31;
        int nt = n >> 4, r = n & 15, kt = kc >> 2, q = kc & 3;
        src = w1 + (size_t)gid * 8;
        dst = ws + WS1_OFF + (size_t)s * 16384 + nt * 4096 + kt * 512 + (q * 16 + r) * 8;
    } else if (gid < 147456) {                   // W2: [s][n(32)][k(64)]
        int g = gid - 131072;
        int s = g >> 8, rem = g & 255;
        int n = rem >> 3, kc = rem & 7;
        int n2 = n >> 4, r = n & 15, kt = kc >> 2, q = kc & 3;
        src = w2 + (size_t)g * 8;
        dst = ws + WS2_OFF + (size_t)s * 2048 + n2 * 1024 + kt * 512 + (q * 16 + r) * 8;
    } else {                                     // W3: [s][n(256)][k(32)]
        int g = gid - 147456;
        int s = g >> 10, rem = g & 1023;
        int n = rem >> 2, q = rem & 3;
        int nt = n >> 4, r = n & 15;
        src = w3 + (size_t)g * 8;
        dst = ws + WS3_OFF + (size_t)s * 8192 + nt * 512 + (q * 16 + r) * 8;
    }
    float4 a = *(const float4*)src;
    float4 b = *(const float4*)(src + 4);
    u16x8 p;
    p[0] = f2bf(a.x); p[1] = f2bf(a.y); p[2] = f2bf(a.z); p[3] = f2bf(a.w);
    p[4] = f2bf(b.x); p[5] = f2bf(b.y); p[6] = f2bf(b.z); p[7] = f2bf(b.w);
    *(u16x8*)dst = p;
}

// ---------------------------------------------------------------------------
// Kernel 2: fused 8-layer x 8-expert MoE MLP — one expert per wave, 8 waves.
// IDENTICAL to round 9 except the occupancy attribute: amdgpu_waves_per_eu(4,4)
// pins the compiler's occupancy TARGET at 4 waves/EU (= the LDS-capped
// residency), giving the scheduler a 128-VGPR budget. Round 9 showed the
// default heuristic targets 8/EU -> 64 VGPRs -> spills (WRITE 16->35 MB) +
// serialized weight loads (MfmaUtil 14). Estimated peak liveness here is
// ~85 VGPRs (G1: xf 32 + w1f 32 + a1 8 + addr) -> fits 128 with no spill.
// ---------------------------------------------------------------------------
__global__ void __launch_bounds__(NTHR)
__attribute__((amdgpu_waves_per_eu(4, 4)))
moe_fused(
    const float* __restrict__ src, const unsigned short* __restrict__ Wf,
    const float* __restrict__ b1, const float* __restrict__ b2,
    const float* __restrict__ b3, const float* __restrict__ masks,
    float* __restrict__ out)
{
    __shared__ __align__(16) unsigned short Xlds[BT * PX];        // 16896 B
    __shared__ __align__(16) unsigned short H1W[8][BT * PH1];     // 36864 B wave-private
    __shared__ __align__(16) unsigned short H2T[8][BT * PH2];     // 20480 B per-expert
    __shared__ float SWlds[BT * PSW];                             //  1152 B
    // total 75392 B -> 2 blocks/CU (150784 <= 160K)

    const int tid  = threadIdx.x;
    const int lane = tid & 63;
    const int wv   = tid >> 6;      // wave id 0..7: expert (G1/G2)
    const int rh   = wv >> 2;       // G3 row-half
    const int cg   = wv & 3;        // G3 col-group
    const int n15  = lane & 15;
    const int q    = lane >> 4;
    const int b0   = blockIdx.x * BT;

    const unsigned short* w3base = Wf + WS3_OFF + cg * 2048 + lane * 8;

    u16x8 xf[2][8];          // persistent x B-frags (dead during G3)
    f32x4 ACC[4];            // 16-row x 64-col accumulator (dead during G1/G2)

    auto stage_softmax = [&](int l) {
        if (tid < BT) {
            const float* mp = masks + ((size_t)l * BSZ + b0 + tid) * ENUM;
            float4 m0 = *(const float4*)mp;
            float4 m1 = *(const float4*)(mp + 4);
            float mv[8] = {m0.x, m0.y, m0.z, m0.w, m1.x, m1.y, m1.z, m1.w};
            float mx = mv[0];
            #pragma unroll
            for (int e = 1; e < 8; ++e) mx = fmaxf(mx, mv[e]);
            float s = 0.f;
            #pragma unroll
            for (int e = 0; e < 8; ++e) { mv[e] = expf(mv[e] - mx); s += mv[e]; }
            float inv = 1.f / s;
            #pragma unroll
            for (int e = 0; e < 8; ++e) SWlds[tid * PSW + e] = mv[e] * inv;
        }
    };

    // ACC = sum_e softmax_w[row][e] * b3[e][col]  (fp32 VALU, once per layer)
    auto acc_init = [&](int l) {
        const float* b3l = b3 + (size_t)l * ENUM * DDIM;
        #pragma unroll
        for (int nt = 0; nt < 4; ++nt) ACC[nt] = Z4;
        #pragma unroll 2
        for (int e2 = 0; e2 < ENUM; ++e2) {
            float swv[4];
            #pragma unroll
            for (int rr = 0; rr < 4; ++rr)
                swv[rr] = SWlds[(rh*16 + q*4 + rr) * PSW + e2];
            #pragma unroll
            for (int nt = 0; nt < 4; ++nt) {
                float bv = b3l[e2 * DDIM + cg*64 + nt*16 + n15];
                #pragma unroll
                for (int rr = 0; rr < 4; ++rr)
                    ACC[nt][rr] += swv[rr] * bv;
            }
        }
    };

    auto xf_read = [&]() {
        #pragma unroll
        for (int mt = 0; mt < 2; ++mt)
            #pragma unroll
            for (int kt = 0; kt < 8; ++kt)
                xf[mt][kt] = *(const u16x8*)
                    &Xlds[(mt*16 + n15) * PX + q*8 + kt*32];
    };
    auto x_write = [&]() {
        #pragma unroll
        for (int nt = 0; nt < 4; ++nt)
            #pragma unroll
            for (int rr = 0; rr < 4; ++rr)
                Xlds[(rh*16 + q*4 + rr) * PX + cg*64 + nt*16 + n15] =
                    f2bf(ACC[nt][rr]);
    };

    // ================= prologue =================
    #pragma unroll
    for (int i = 0; i < 2; ++i) {                // stage layer-0 x (bf16)
        int o = (i * NTHR + tid) * 8;
        int r = o >> 8, c = o & 255;
        const float* p = src + (size_t)(b0 + r) * DDIM + c;
        float4 f0 = *(const float4*)(p);
        float4 f1 = *(const float4*)(p + 4);
        u16x8 pk;
        pk[0] = f2bf(f0.x); pk[1] = f2bf(f0.y); pk[2] = f2bf(f0.z); pk[3] = f2bf(f0.w);
        pk[4] = f2bf(f1.x); pk[5] = f2bf(f1.y); pk[6] = f2bf(f1.z); pk[7] = f2bf(f1.w);
        *(u16x8*)&Xlds[r * PX + c] = pk;
    }
    stage_softmax(0);
    __syncthreads();
    xf_read();

    // ================= layer loop =================
    #pragma unroll 1
    for (int l = 0; l < LNUM; ++l) {
        const int sbase = l * ENUM;
        const int s = sbase + wv;        // this wave's expert step

        // ===== G1: h1 = relu(x @ W1^T + b1), 4 feat-tiles (barrier-free) =====
        // lane -> feats ft*16+q*4+rr, rows mt*16+n15 (transposed MFMA)
        #pragma unroll
        for (int ft = 0; ft < 4; ++ft) {
            u16x8 w1f[8];
            const unsigned short* p1 =
                Wf + WS1_OFF + (size_t)s * 16384 + ft * 4096 + lane * 8;
            #pragma unroll
            for (int kt = 0; kt < 8; ++kt)
                w1f[kt] = *(const u16x8*)(p1 + kt * 512);
            f32x4 a1[2] = {Z4, Z4};
            #pragma unroll
            for (int kt = 0; kt < 8; ++kt) {
                a1[0] = mfma16(w1f[kt], xf[0][kt], a1[0]);
                a1[1] = mfma16(w1f[kt], xf[1][kt], a1[1]);
            }
            const float4 bb1 = *(const float4*)(b1 + s * 64 + ft * 16 + q * 4);
            #pragma unroll
            for (int mt = 0; mt < 2; ++mt) {
                u16x4 pk;
                #pragma unroll
                for (int rr = 0; rr < 4; ++rr)
                    pk[rr] = f2bf(fmaxf(a1[mt][rr] + bb1[rr], 0.f));
                *(u16x4*)&H1W[wv][(mt*16 + n15) * PH1 + ft*16 + q*4] = pk;
            }
        }

        // ===== G2: h2 = relu(h1 @ W2^T + b2) * sw[wv] (intra-wave, no bar) =====
        {
            u16x8 w2f[2][2];
            const unsigned short* p2 = Wf + WS2_OFF + (size_t)s * 2048 + lane * 8;
            #pragma unroll
            for (int f2 = 0; f2 < 2; ++f2)
                #pragma unroll
                for (int kt = 0; kt < 2; ++kt)
                    w2f[f2][kt] = *(const u16x8*)(p2 + f2*1024 + kt*512);
            u16x8 h1f[2][2];
            #pragma unroll
            for (int mt = 0; mt < 2; ++mt)
                #pragma unroll
                for (int kt = 0; kt < 2; ++kt)
                    h1f[mt][kt] = *(const u16x8*)
                        &H1W[wv][(mt*16 + n15) * PH1 + q*8 + kt*32];
            f32x4 a2[2][2] = {{Z4, Z4}, {Z4, Z4}};
            #pragma unroll
            for (int f2 = 0; f2 < 2; ++f2)
                #pragma unroll
                for (int mt = 0; mt < 2; ++mt)
                    #pragma unroll
                    for (int kt = 0; kt < 2; ++kt)
                        a2[f2][mt] = mfma16(w2f[f2][kt], h1f[mt][kt], a2[f2][mt]);
            float swv[2];
            #pragma unroll
            for (int mt = 0; mt < 2; ++mt)
                swv[mt] = SWlds[(mt*16 + n15) * PSW + wv];
            #pragma unroll
            for (int f2 = 0; f2 < 2; ++f2) {
                const float4 bb2 = *(const float4*)(b2 + s * 32 + f2 * 16 + q * 4);
                #pragma unroll
                for (int mt = 0; mt < 2; ++mt) {
                    u16x4 pk;
                    #pragma unroll
                    for (int rr = 0; rr < 4; ++rr)
                        pk[rr] = f2bf(fmaxf(a2[f2][mt][rr] + bb2[rr], 0.f) * swv[mt]);
                    *(u16x4*)&H2T[wv][(mt*16 + n15) * PH2 + f2*16 + q*4] = pk;
                }
            }
        }

        lbar();                     // all 8 experts' h2 ready (only mid-layer barrier)

        // ===== ACC init (deferred: ACC dead during G1/G2) =====
        acc_init(l);

        // ===== G3: all 8 experts, rows rh*16..+15, cols cg*64..+63 =====
        #pragma unroll
        for (int e = 0; e < ENUM; ++e) {
            u16x8 w3f[4];
            const unsigned short* p3 = w3base + (size_t)(sbase + e) * 8192;
            #pragma unroll
            for (int nt = 0; nt < 4; ++nt)
                w3f[nt] = *(const u16x8*)(p3 + nt * 512);
            u16x8 h = *(const u16x8*)&H2T[e][(rh*16 + n15) * PH2 + q*8];
            #pragma unroll
            for (int nt = 0; nt < 4; ++nt)
                ACC[nt] = mfma16(h, w3f[nt], ACC[nt]);
        }

        // ===== layer transition =====
        if (l < LNUM - 1) {
            x_write();
            lbar();
            xf_read();
            stage_softmax(l + 1);
            lbar();
        }
    }

    // ================= final store (fp32) =================
    #pragma unroll
    for (int nt = 0; nt < 4; ++nt)
        #pragma unroll
        for (int rr = 0; rr < 4; ++rr)
            out[(size_t)(b0 + rh*16 + q*4 + rr) * DDIM
                + cg*64 + nt*16 + n15] = ACC[nt][rr];
}

extern "C" void kernel_launch(void* const* d_in, const int* in_sizes, int n_in,
                              void* d_out, int out_size, void* d_ws, size_t ws_size,
                              hipStream_t stream) {
    const float* src   = (const float*)d_in[0];
    const float* W1    = (const float*)d_in[1];
    const float* b1    = (const float*)d_in[2];
    const float* W2    = (const float*)d_in[3];
    const float* b2    = (const float*)d_in[4];
    const float* W3    = (const float*)d_in[5];
    const float* b3    = (const float*)d_in[6];
    const float* masks = (const float*)d_in[7];
    float* out = (float*)d_out;
    unsigned short* ws = (unsigned short*)d_ws;   // needs 3,407,872 B

    hipLaunchKernelGGL(cvt_w_frag, dim3(832), dim3(256), 0, stream, W1, W2, W3, ws);
    hipLaunchKernelGGL(moe_fused, dim3(BSZ / BT), dim3(NTHR), 0, stream,
                       src, ws, b1, b2, b3, masks, out);
}

// Round 11
// 227.346 us; speedup vs baseline: 1.0049x; 1.0045x over previous
//
#include <hip/hip_runtime.h>
#include <hip/hip_bf16.h>

// Problem constants
#define LNUM 8
#define ENUM 8
#define DDIM 256
#define BSZ  16384
#define H1N  64
#define H2N  32

#define BT   32     // rows per block  (grid 512 -> 2 blocks/CU, LDS-capped)
#define NTHR 512    // 8 waves: one expert per wave -> 4 waves/SIMD

// LDS pitches (u16 elements); odd 16B-granule strides -> conflict-light
#define PX   264    // x tile (D + 8)
#define PH1  72     // h1 tile pitch (H1 + 8)   [row][feat]
#define PH2  40     // h2 tile pitch (H2 + 8)   [row][feat]
#define PSW  9      // softmax weights pitch (floats)

// ws element offsets (u16 elems) for fragment-ordered weights
#define WS1_OFF 0           // 64 steps * 16384 elems
#define WS2_OFF 1048576     // 64 steps * 2048
#define WS3_OFF 1179648     // 64 steps * 8192

typedef float f32x4 __attribute__((ext_vector_type(4)));
typedef unsigned short u16x8 __attribute__((ext_vector_type(8)));
typedef unsigned short u16x4 __attribute__((ext_vector_type(4)));
typedef __bf16 bf16x8 __attribute__((ext_vector_type(8)));

#define Z4 ((f32x4){0.f, 0.f, 0.f, 0.f})

// f32 -> bf16 RTNE via native cast (compiler pairs into v_cvt_pk_bf16_f32).
static __device__ __forceinline__ unsigned short f2bf(float f) {
    __bf16 h = (__bf16)f;
    return __builtin_bit_cast(unsigned short, h);
}

// D[m][n] = sum_k A[m][k]*B[n][k] + C : A supplies m, B supplies n, frags are
// symmetric [idx16][K] -> swapping args transposes the output tile.
static __device__ __forceinline__ f32x4 mfma16(u16x8 a, u16x8 b, f32x4 c) {
    return __builtin_amdgcn_mfma_f32_16x16x32_bf16(
        __builtin_bit_cast(bf16x8, a), __builtin_bit_cast(bf16x8, b), c, 0, 0, 0);
}

// Barrier with lgkmcnt-only drain: LDS producer/consumer ordering preserved,
// in-flight GLOBAL loads are NOT drained (vs __syncthreads' vmcnt(0)).
// Safe: all inter-wave data flows through LDS; no global stores in the loop.
// HW-validated rounds 2/4/5/6/7/8/9/10.
static __device__ __forceinline__ void lbar() {
    asm volatile("s_waitcnt lgkmcnt(0)" ::: "memory");
    __builtin_amdgcn_s_barrier();
    asm volatile("" ::: "memory");
}

// ---------------------------------------------------------------------------
// Kernel 1: fp32 weights -> bf16 B-fragment layout. Unchanged.
// Fragment: 64 lanes x 8 elems; slot (q*16+r) holds W[n0+r][k0+q*8 .. +7].
// ---------------------------------------------------------------------------
__global__ __launch_bounds__(256) void cvt_w_frag(
    const float* __restrict__ w1, const float* __restrict__ w2,
    const float* __restrict__ w3, unsigned short* __restrict__ ws)
{
    int gid = blockIdx.x * 256 + threadIdx.x;
    const float* src;
    unsigned short* dst;
    if (gid < 131072) {                          // W1: [s][n(64)][k(256)]
        int s = gid >> 11, rem = gid & 2047;
        int n = rem >> 5, kc = rem & 31;
        int nt = n >> 4, r = n & 15, kt = kc >> 2, q = kc & 3;
        src = w1 + (size_t)gid * 8;
        dst = ws + WS1_OFF + (size_t)s * 16384 + nt * 4096 + kt * 512 + (q * 16 + r) * 8;
    } else if (gid < 147456) {                   // W2: [s][n(32)][k(64)]
        int g = gid - 131072;
        int s = g >> 8, rem = g & 255;
        int n = rem >> 3, kc = rem & 7;
        int n2 = n >> 4, r = n & 15, kt = kc >> 2, q = kc & 3;
        src = w2 + (size_t)g * 8;
        dst = ws + WS2_OFF + (size_t)s * 2048 + n2 * 1024 + kt * 512 + (q * 16 + r) * 8;
    } else {                                     // W3: [s][n(256)][k(32)]
        int g = gid - 147456;
        int s = g >> 10, rem = g & 1023;
        int n = rem >> 2, q = rem & 3;
        int nt = n >> 4, r = n & 15;
        src = w3 + (size_t)g * 8;
        dst = ws + WS3_OFF + (size_t)s * 8192 + nt * 512 + (q * 16 + r) * 8;
    }
    float4 a = *(const float4*)src;
    float4 b = *(const float4*)(src + 4);
    u16x8 p;
    p[0] = f2bf(a.x); p[1] = f2bf(a.y); p[2] = f2bf(a.z); p[3] = f2bf(a.w);
    p[4] = f2bf(b.x); p[5] = f2bf(b.y); p[6] = f2bf(b.z); p[7] = f2bf(b.w);
    *(u16x8*)dst = p;
}

// ---------------------------------------------------------------------------
// Kernel 2: fused 8-layer x 8-expert MoE MLP — one expert per wave, 8 waves.
// IDENTICAL to round 9/10 except G1 STREAMS its W1 fragments (one u16x8 per
// kt) instead of batching w1f[8]. Liveness audit: the w1f[8] batch (32 regs)
// overlapped live xf[2][8] (32 regs) -> >64 peak -> the 64-VGPR occupancy
// target the compiler insists on for this 512-thread kernel forced spills
// (R9/R10: WRITE 16->35 MB, MfmaUtil 14). Streaming caps G1 peak at
// ~xf 32 + in-flight loads 8-16 + acc 8 -> fits 64 cleanly. The per-load
// latency left exposed intra-wave is covered by the structure's 4 waves/SIMD
// (45% occupancy, measured). G2 (xf dead there: ~56 live) and G3 (ACC 16 +
// w3f 16) already fit. No other changes.
// ---------------------------------------------------------------------------
__global__ __launch_bounds__(NTHR, 4) void moe_fused(
    const float* __restrict__ src, const unsigned short* __restrict__ Wf,
    const float* __restrict__ b1, const float* __restrict__ b2,
    const float* __restrict__ b3, const float* __restrict__ masks,
    float* __restrict__ out)
{
    __shared__ __align__(16) unsigned short Xlds[BT * PX];        // 16896 B
    __shared__ __align__(16) unsigned short H1W[8][BT * PH1];     // 36864 B wave-private
    __shared__ __align__(16) unsigned short H2T[8][BT * PH2];     // 20480 B per-expert
    __shared__ float SWlds[BT * PSW];                             //  1152 B
    // total 75392 B -> 2 blocks/CU (150784 <= 160K)

    const int tid  = threadIdx.x;
    const int lane = tid & 63;
    const int wv   = tid >> 6;      // wave id 0..7: expert (G1/G2)
    const int rh   = wv >> 2;       // G3 row-half
    const int cg   = wv & 3;        // G3 col-group
    const int n15  = lane & 15;
    const int q    = lane >> 4;
    const int b0   = blockIdx.x * BT;

    const unsigned short* w3base = Wf + WS3_OFF + cg * 2048 + lane * 8;

    u16x8 xf[2][8];          // persistent x B-frags (dead during G2/G3)
    f32x4 ACC[4];            // 16-row x 64-col accumulator (dead during G1/G2)

    auto stage_softmax = [&](int l) {
        if (tid < BT) {
            const float* mp = masks + ((size_t)l * BSZ + b0 + tid) * ENUM;
            float4 m0 = *(const float4*)mp;
            float4 m1 = *(const float4*)(mp + 4);
            float mv[8] = {m0.x, m0.y, m0.z, m0.w, m1.x, m1.y, m1.z, m1.w};
            float mx = mv[0];
            #pragma unroll
            for (int e = 1; e < 8; ++e) mx = fmaxf(mx, mv[e]);
            float s = 0.f;
            #pragma unroll
            for (int e = 0; e < 8; ++e) { mv[e] = expf(mv[e] - mx); s += mv[e]; }
            float inv = 1.f / s;
            #pragma unroll
            for (int e = 0; e < 8; ++e) SWlds[tid * PSW + e] = mv[e] * inv;
        }
    };

    // ACC = sum_e softmax_w[row][e] * b3[e][col]  (fp32 VALU, once per layer)
    auto acc_init = [&](int l) {
        const float* b3l = b3 + (size_t)l * ENUM * DDIM;
        #pragma unroll
        for (int nt = 0; nt < 4; ++nt) ACC[nt] = Z4;
        #pragma unroll 2
        for (int e2 = 0; e2 < ENUM; ++e2) {
            float swv[4];
            #pragma unroll
            for (int rr = 0; rr < 4; ++rr)
                swv[rr] = SWlds[(rh*16 + q*4 + rr) * PSW + e2];
            #pragma unroll
            for (int nt = 0; nt < 4; ++nt) {
                float bv = b3l[e2 * DDIM + cg*64 + nt*16 + n15];
                #pragma unroll
                for (int rr = 0; rr < 4; ++rr)
                    ACC[nt][rr] += swv[rr] * bv;
            }
        }
    };

    auto xf_read = [&]() {
        #pragma unroll
        for (int mt = 0; mt < 2; ++mt)
            #pragma unroll
            for (int kt = 0; kt < 8; ++kt)
                xf[mt][kt] = *(const u16x8*)
                    &Xlds[(mt*16 + n15) * PX + q*8 + kt*32];
    };
    auto x_write = [&]() {
        #pragma unroll
        for (int nt = 0; nt < 4; ++nt)
            #pragma unroll
            for (int rr = 0; rr < 4; ++rr)
                Xlds[(rh*16 + q*4 + rr) * PX + cg*64 + nt*16 + n15] =
                    f2bf(ACC[nt][rr]);
    };

    // ================= prologue =================
    #pragma unroll
    for (int i = 0; i < 2; ++i) {                // stage layer-0 x (bf16)
        int o = (i * NTHR + tid) * 8;
        int r = o >> 8, c = o & 255;
        const float* p = src + (size_t)(b0 + r) * DDIM + c;
        float4 f0 = *(const float4*)(p);
        float4 f1 = *(const float4*)(p + 4);
        u16x8 pk;
        pk[0] = f2bf(f0.x); pk[1] = f2bf(f0.y); pk[2] = f2bf(f0.z); pk[3] = f2bf(f0.w);
        pk[4] = f2bf(f1.x); pk[5] = f2bf(f1.y); pk[6] = f2bf(f1.z); pk[7] = f2bf(f1.w);
        *(u16x8*)&Xlds[r * PX + c] = pk;
    }
    stage_softmax(0);
    __syncthreads();
    xf_read();

    // ================= layer loop =================
    #pragma unroll 1
    for (int l = 0; l < LNUM; ++l) {
        const int sbase = l * ENUM;
        const int s = sbase + wv;        // this wave's expert step

        // ===== G1: h1 = relu(x @ W1^T + b1), 4 feat-tiles (barrier-free) =====
        // W1 fragments STREAMED (one u16x8 per kt) to keep peak liveness
        // under the 64-VGPR budget; 4 waves/SIMD cover the load latency.
        // lane -> feats ft*16+q*4+rr, rows mt*16+n15 (transposed MFMA)
        #pragma unroll
        for (int ft = 0; ft < 4; ++ft) {
            const unsigned short* p1 =
                Wf + WS1_OFF + (size_t)s * 16384 + ft * 4096 + lane * 8;
            f32x4 a1[2] = {Z4, Z4};
            #pragma unroll
            for (int kt = 0; kt < 8; ++kt) {
                u16x8 w1f = *(const u16x8*)(p1 + kt * 512);
                a1[0] = mfma16(w1f, xf[0][kt], a1[0]);
                a1[1] = mfma16(w1f, xf[1][kt], a1[1]);
            }
            const float4 bb1 = *(const float4*)(b1 + s * 64 + ft * 16 + q * 4);
            #pragma unroll
            for (int mt = 0; mt < 2; ++mt) {
                u16x4 pk;
                #pragma unroll
                for (int rr = 0; rr < 4; ++rr)
                    pk[rr] = f2bf(fmaxf(a1[mt][rr] + bb1[rr], 0.f));
                *(u16x4*)&H1W[wv][(mt*16 + n15) * PH1 + ft*16 + q*4] = pk;
            }
        }

        // ===== G2: h2 = relu(h1 @ W2^T + b2) * sw[wv] (intra-wave, no bar) =====
        {
            u16x8 w2f[2][2];
            const unsigned short* p2 = Wf + WS2_OFF + (size_t)s * 2048 + lane * 8;
            #pragma unroll
            for (int f2 = 0; f2 < 2; ++f2)
                #pragma unroll
                for (int kt = 0; kt < 2; ++kt)
                    w2f[f2][kt] = *(const u16x8*)(p2 + f2*1024 + kt*512);
            u16x8 h1f[2][2];
            #pragma unroll
            for (int mt = 0; mt < 2; ++mt)
                #pragma unroll
                for (int kt = 0; kt < 2; ++kt)
                    h1f[mt][kt] = *(const u16x8*)
                        &H1W[wv][(mt*16 + n15) * PH1 + q*8 + kt*32];
            f32x4 a2[2][2] = {{Z4, Z4}, {Z4, Z4}};
            #pragma unroll
            for (int f2 = 0; f2 < 2; ++f2)
                #pragma unroll
                for (int mt = 0; mt < 2; ++mt)
                    #pragma unroll
                    for (int kt = 0; kt < 2; ++kt)
                        a2[f2][mt] = mfma16(w2f[f2][kt], h1f[mt][kt], a2[f2][mt]);
            float swv[2];
            #pragma unroll
            for (int mt = 0; mt < 2; ++mt)
                swv[mt] = SWlds[(mt*16 + n15) * PSW + wv];
            #pragma unroll
            for (int f2 = 0; f2 < 2; ++f2) {
                const float4 bb2 = *(const float4*)(b2 + s * 32 + f2 * 16 + q * 4);
                #pragma unroll
                for (int mt = 0; mt < 2; ++mt) {
                    u16x4 pk;
                    #pragma unroll
                    for (int rr = 0; rr < 4; ++rr)
                        pk[rr] = f2bf(fmaxf(a2[f2][mt][rr] + bb2[rr], 0.f) * swv[mt]);
                    *(u16x4*)&H2T[wv][(mt*16 + n15) * PH2 + f2*16 + q*4] = pk;
                }
            }
        }

        lbar();                     // all 8 experts' h2 ready (only mid-layer barrier)

        // ===== ACC init (deferred: ACC dead during G1/G2) =====
        acc_init(l);

        // ===== G3: all 8 experts, rows rh*16..+15, cols cg*64..+63 =====
        #pragma unroll
        for (int e = 0; e < ENUM; ++e) {
            u16x8 w3f[4];
            const unsigned short* p3 = w3base + (size_t)(sbase + e) * 8192;
            #pragma unroll
            for (int nt = 0; nt < 4; ++nt)
                w3f[nt] = *(const u16x8*)(p3 + nt * 512);
            u16x8 h = *(const u16x8*)&H2T[e][(rh*16 + n15) * PH2 + q*8];
            #pragma unroll
            for (int nt = 0; nt < 4; ++nt)
                ACC[nt] = mfma16(h, w3f[nt], ACC[nt]);
        }

        // ===== layer transition =====
        if (l < LNUM - 1) {
            x_write();
            lbar();
            xf_read();
            stage_softmax(l + 1);
            lbar();
        }
    }

    // ================= final store (fp32) =================
    #pragma unroll
    for (int nt = 0; nt < 4; ++nt)
        #pragma unroll
        for (int rr = 0; rr < 4; ++rr)
            out[(size_t)(b0 + rh*16 + q*4 + rr) * DDIM
                + cg*64 + nt*16 + n15] = ACC[nt][rr];
}

extern "C" void kernel_launch(void* const* d_in, const int* in_sizes, int n_in,
                              void* d_out, int out_size, void* d_ws, size_t ws_size,
                              hipStream_t stream) {
    const float* src   = (const float*)d_in[0];
    const float* W1    = (const float*)d_in[1];
    const float* b1    = (const float*)d_in[2];
    const float* W2    = (const float*)d_in[3];
    const float* b2    = (const float*)d_in[4];
    const float* W3    = (const float*)d_in[5];
    const float* b3    = (const float*)d_in[6];
    const float* masks = (const float*)d_in[7];
    float* out = (float*)d_out;
    unsigned short* ws = (unsigned short*)d_ws;   // needs 3,407,872 B

    hipLaunchKernelGGL(cvt_w_frag, dim3(832), dim3(256), 0, stream, W1, W2, W3, ws);
    hipLaunchKernelGGL(moe_fused, dim3(BSZ / BT), dim3(NTHR), 0, stream,
                       src, ws, b1, b2, b3, masks, out);
}

// Round 12
// 189.054 us; speedup vs baseline: 1.2084x; 1.2025x over previous
//
#include <hip/hip_runtime.h>
#include <hip/hip_bf16.h>

// Problem constants
#define LNUM 8
#define ENUM 8
#define DDIM 256
#define BSZ  16384
#define H1N  64
#define H2N  32

#define BT   32     // rows per block  (grid 512 -> 2 blocks/CU)
#define NTHR 256    // 4 waves (256-thread shape: compiler allocates ~100 VGPR)

// LDS pitches (u16 elements); odd 16B-granule strides -> conflict-light
#define PX   264    // x tile (D + 8)
#define PH1  72     // h1 tile pitch (H1 + 8)   [row][feat]
#define PH2  40     // h2 tile pitch (H2 + 8)   [row][feat]
#define PSW  9      // softmax weights pitch (floats)

// ws element offsets (u16 elems) for fragment-ordered weights
#define WS1_OFF 0           // 64 steps * 16384 elems
#define WS2_OFF 1048576     // 64 steps * 2048
#define WS3_OFF 1179648     // 64 steps * 8192

typedef float f32x4 __attribute__((ext_vector_type(4)));
typedef unsigned short u16x8 __attribute__((ext_vector_type(8)));
typedef unsigned short u16x4 __attribute__((ext_vector_type(4)));
typedef __bf16 bf16x8 __attribute__((ext_vector_type(8)));

#define Z4 ((f32x4){0.f, 0.f, 0.f, 0.f})

// f32 -> bf16 RTNE via native cast (compiler pairs into v_cvt_pk_bf16_f32).
static __device__ __forceinline__ unsigned short f2bf(float f) {
    __bf16 h = (__bf16)f;
    return __builtin_bit_cast(unsigned short, h);
}

// D[m][n] = sum_k A[m][k]*B[n][k] + C : A supplies m, B supplies n, frags are
// symmetric [idx16][K] -> swapping args transposes the output tile.
static __device__ __forceinline__ f32x4 mfma16(u16x8 a, u16x8 b, f32x4 c) {
    return __builtin_amdgcn_mfma_f32_16x16x32_bf16(
        __builtin_bit_cast(bf16x8, a), __builtin_bit_cast(bf16x8, b), c, 0, 0, 0);
}

// Barrier with lgkmcnt-only drain: LDS producer/consumer ordering preserved,
// in-flight GLOBAL loads are NOT drained (vs __syncthreads' vmcnt(0)).
// Safe: all inter-wave data flows through LDS; no global stores in the loop.
// HW-validated rounds 2/4/5/6/7/8/9/10/11.
static __device__ __forceinline__ void lbar() {
    asm volatile("s_waitcnt lgkmcnt(0)" ::: "memory");
    __builtin_amdgcn_s_barrier();
    asm volatile("" ::: "memory");
}

// ---------------------------------------------------------------------------
// Kernel 1: fp32 weights -> bf16 B-fragment layout. Unchanged.
// Fragment: 64 lanes x 8 elems; slot (q*16+r) holds W[n0+r][k0+q*8 .. +7].
// ---------------------------------------------------------------------------
__global__ __launch_bounds__(256) void cvt_w_frag(
    const float* __restrict__ w1, const float* __restrict__ w2,
    const float* __restrict__ w3, unsigned short* __restrict__ ws)
{
    int gid = blockIdx.x * 256 + threadIdx.x;
    const float* src;
    unsigned short* dst;
    if (gid < 131072) {                          // W1: [s][n(64)][k(256)]
        int s = gid >> 11, rem = gid & 2047;
        int n = rem >> 5, kc = rem & 31;
        int nt = n >> 4, r = n & 15, kt = kc >> 2, q = kc & 3;
        src = w1 + (size_t)gid * 8;
        dst = ws + WS1_OFF + (size_t)s * 16384 + nt * 4096 + kt * 512 + (q * 16 + r) * 8;
    } else if (gid < 147456) {                   // W2: [s][n(32)][k(64)]
        int g = gid - 131072;
        int s = g >> 8, rem = g & 255;
        int n = rem >> 3, kc = rem & 7;
        int n2 = n >> 4, r = n & 15, kt = kc >> 2, q = kc & 3;
        src = w2 + (size_t)g * 8;
        dst = ws + WS2_OFF + (size_t)s * 2048 + n2 * 1024 + kt * 512 + (q * 16 + r) * 8;
    } else {                                     // W3: [s][n(256)][k(32)]
        int g = gid - 147456;
        int s = g >> 10, rem = g & 1023;
        int n = rem >> 2, q = rem & 3;
        int nt = n >> 4, r = n & 15;
        src = w3 + (size_t)g * 8;
        dst = ws + WS3_OFF + (size_t)s * 8192 + nt * 512 + (q * 16 + r) * 8;
    }
    float4 a = *(const float4*)src;
    float4 b = *(const float4*)(src + 4);
    u16x8 p;
    p[0] = f2bf(a.x); p[1] = f2bf(a.y); p[2] = f2bf(a.z); p[3] = f2bf(a.w);
    p[4] = f2bf(b.x); p[5] = f2bf(b.y); p[6] = f2bf(b.z); p[7] = f2bf(b.w);
    *(u16x8*)dst = p;
}

// ---------------------------------------------------------------------------
// Kernel 2: fused 8-layer x 8-expert MoE MLP — R8 structure (4 waves, wave wv
// owns experts {wv, wv+4}; wave-private H1 transpose, 3 barriers/layer) with
// G1 INTERLEAVED across the two experts: per (ft,kt) load wA+wB and issue 4
// independent MFMA chains (R8 ran experts sequentially = 2 chains). Doubles
// the MFMA cover per weight load so the in-order wave rides out L2 latency.
// H1W doubled to hold both experts' h1 (LDS 75392 B -> still 2 blocks/CU).
// G2/G3 byte-identical to R8 (liveness there already near the 128 cap).
// ---------------------------------------------------------------------------
__global__ __launch_bounds__(NTHR, 2) void moe_fused(
    const float* __restrict__ src, const unsigned short* __restrict__ Wf,
    const float* __restrict__ b1, const float* __restrict__ b2,
    const float* __restrict__ b3, const float* __restrict__ masks,
    float* __restrict__ out)
{
    __shared__ __align__(16) unsigned short Xlds[BT * PX];        // 16896 B
    __shared__ __align__(16) unsigned short H1W[4][2][BT * PH1];  // 36864 B [wave][expert]
    __shared__ __align__(16) unsigned short H2T[8][BT * PH2];     // 20480 B per-expert
    __shared__ float SWlds[BT * PSW];                             //  1152 B
    // total 75392 B -> 2 blocks/CU (150784 <= 163840)

    const int tid  = threadIdx.x;
    const int lane = tid & 63;
    const int wv   = tid >> 6;      // wave id 0..3: experts {wv, wv+4}; G3 col grp
    const int n15  = lane & 15;
    const int q    = lane >> 4;
    const int b0   = blockIdx.x * BT;

    const unsigned short* w3base = Wf + WS3_OFF + wv * 2048 + lane * 8;

    u16x8 xf[2][8];          // persistent x B-frags (live across the layer)
    f32x4 ACC[2][4];         // output accumulator (dead during G1/G2)

    auto stage_softmax = [&](int l) {
        if (tid < BT) {
            const float* mp = masks + ((size_t)l * BSZ + b0 + tid) * ENUM;
            float4 m0 = *(const float4*)mp;
            float4 m1 = *(const float4*)(mp + 4);
            float mv[8] = {m0.x, m0.y, m0.z, m0.w, m1.x, m1.y, m1.z, m1.w};
            float mx = mv[0];
            #pragma unroll
            for (int e = 1; e < 8; ++e) mx = fmaxf(mx, mv[e]);
            float s = 0.f;
            #pragma unroll
            for (int e = 0; e < 8; ++e) { mv[e] = expf(mv[e] - mx); s += mv[e]; }
            float inv = 1.f / s;
            #pragma unroll
            for (int e = 0; e < 8; ++e) SWlds[tid * PSW + e] = mv[e] * inv;
        }
    };

    // ACC = sum_e softmax_w[row][e] * b3[e][col]  (fp32 VALU, once per layer)
    auto acc_init = [&](int l) {
        const float* b3l = b3 + (size_t)l * ENUM * DDIM;
        #pragma unroll
        for (int mt = 0; mt < 2; ++mt)
            #pragma unroll
            for (int nt = 0; nt < 4; ++nt) ACC[mt][nt] = Z4;
        #pragma unroll 2
        for (int e2 = 0; e2 < ENUM; ++e2) {
            float swv[2][4];
            #pragma unroll
            for (int mt = 0; mt < 2; ++mt)
                #pragma unroll
                for (int rr = 0; rr < 4; ++rr)
                    swv[mt][rr] = SWlds[(mt*16 + q*4 + rr) * PSW + e2];
            #pragma unroll
            for (int nt = 0; nt < 4; ++nt) {
                float bv = b3l[e2 * DDIM + wv*64 + nt*16 + n15];
                #pragma unroll
                for (int mt = 0; mt < 2; ++mt)
                    #pragma unroll
                    for (int rr = 0; rr < 4; ++rr)
                        ACC[mt][nt][rr] += swv[mt][rr] * bv;
            }
        }
    };

    auto xf_read = [&]() {
        #pragma unroll
        for (int mt = 0; mt < 2; ++mt)
            #pragma unroll
            for (int kt = 0; kt < 8; ++kt)
                xf[mt][kt] = *(const u16x8*)
                    &Xlds[(mt*16 + n15) * PX + q*8 + kt*32];
    };
    auto x_write = [&]() {
        #pragma unroll
        for (int mt = 0; mt < 2; ++mt)
            #pragma unroll
            for (int nt = 0; nt < 4; ++nt)
                #pragma unroll
                for (int rr = 0; rr < 4; ++rr)
                    Xlds[(mt*16 + q*4 + rr) * PX + wv*64 + nt*16 + n15] =
                        f2bf(ACC[mt][nt][rr]);
    };

    // ================= prologue =================
    #pragma unroll
    for (int i = 0; i < 4; ++i) {                // stage layer-0 x (bf16)
        int o = (i * NTHR + tid) * 8;
        int r = o >> 8, c = o & 255;
        const float* p = src + (size_t)(b0 + r) * DDIM + c;
        float4 f0 = *(const float4*)(p);
        float4 f1 = *(const float4*)(p + 4);
        u16x8 pk;
        pk[0] = f2bf(f0.x); pk[1] = f2bf(f0.y); pk[2] = f2bf(f0.z); pk[3] = f2bf(f0.w);
        pk[4] = f2bf(f1.x); pk[5] = f2bf(f1.y); pk[6] = f2bf(f1.z); pk[7] = f2bf(f1.w);
        *(u16x8*)&Xlds[r * PX + c] = pk;
    }
    stage_softmax(0);
    __syncthreads();
    xf_read();

    // ================= layer loop =================
    #pragma unroll 1
    for (int l = 0; l < LNUM; ++l) {
        const int sbase = l * ENUM;
        const int sA = sbase + wv;          // expert A = wv
        const int sB = sbase + wv + 4;      // expert B = wv+4

        // ===== G1 both experts INTERLEAVED, 4 feat-tiles (barrier-free) =====
        // Per (ft,kt): 2 loads feed 4 independent MFMA chains -> 2x the MFMA
        // cover per load vs the sequential form. Transient regs: wA,wB (8).
        // lane -> feats ft*16+q*4+rr, rows mt*16+n15 (transposed MFMA)
        #pragma unroll
        for (int ft = 0; ft < 4; ++ft) {
            const unsigned short* pA =
                Wf + WS1_OFF + (size_t)sA * 16384 + ft * 4096 + lane * 8;
            const unsigned short* pB =
                Wf + WS1_OFF + (size_t)sB * 16384 + ft * 4096 + lane * 8;
            f32x4 aA[2] = {Z4, Z4}, aB[2] = {Z4, Z4};
            #pragma unroll
            for (int kt = 0; kt < 8; ++kt) {
                u16x8 wA = *(const u16x8*)(pA + kt * 512);
                u16x8 wB = *(const u16x8*)(pB + kt * 512);
                aA[0] = mfma16(wA, xf[0][kt], aA[0]);
                aB[0] = mfma16(wB, xf[0][kt], aB[0]);
                aA[1] = mfma16(wA, xf[1][kt], aA[1]);
                aB[1] = mfma16(wB, xf[1][kt], aB[1]);
            }
            const float4 bbA = *(const float4*)(b1 + sA * 64 + ft * 16 + q * 4);
            const float4 bbB = *(const float4*)(b1 + sB * 64 + ft * 16 + q * 4);
            #pragma unroll
            for (int mt = 0; mt < 2; ++mt) {
                u16x4 pkA, pkB;
                #pragma unroll
                for (int rr = 0; rr < 4; ++rr) {
                    pkA[rr] = f2bf(fmaxf(aA[mt][rr] + bbA[rr], 0.f));
                    pkB[rr] = f2bf(fmaxf(aB[mt][rr] + bbB[rr], 0.f));
                }
                int row = mt*16 + n15;
                *(u16x4*)&H1W[wv][0][row * PH1 + ft*16 + q*4] = pkA;
                *(u16x4*)&H1W[wv][1][row * PH1 + ft*16 + q*4] = pkB;
            }
        }

        // ===== G2 per expert (intra-wave h1 read, no barrier) =====
        #pragma unroll
        for (int pe = 0; pe < 2; ++pe) {
            const int e = wv + pe * 4;
            const int s = sbase + e;
            u16x8 w2f[2][2];
            const unsigned short* p2 = Wf + WS2_OFF + (size_t)s * 2048 + lane * 8;
            #pragma unroll
            for (int f2 = 0; f2 < 2; ++f2)
                #pragma unroll
                for (int kt = 0; kt < 2; ++kt)
                    w2f[f2][kt] = *(const u16x8*)(p2 + f2*1024 + kt*512);
            u16x8 h1f[2][2];
            #pragma unroll
            for (int mt = 0; mt < 2; ++mt)
                #pragma unroll
                for (int kt = 0; kt < 2; ++kt)
                    h1f[mt][kt] = *(const u16x8*)
                        &H1W[wv][pe][(mt*16 + n15) * PH1 + q*8 + kt*32];
            f32x4 a2[2][2] = {{Z4, Z4}, {Z4, Z4}};
            #pragma unroll
            for (int f2 = 0; f2 < 2; ++f2)
                #pragma unroll
                for (int mt = 0; mt < 2; ++mt)
                    #pragma unroll
                    for (int kt = 0; kt < 2; ++kt)
                        a2[f2][mt] = mfma16(w2f[f2][kt], h1f[mt][kt], a2[f2][mt]);
            float swv[2];
            #pragma unroll
            for (int mt = 0; mt < 2; ++mt)
                swv[mt] = SWlds[(mt*16 + n15) * PSW + e];
            #pragma unroll
            for (int f2 = 0; f2 < 2; ++f2) {
                const float4 bb2 = *(const float4*)(b2 + s * 32 + f2 * 16 + q * 4);
                #pragma unroll
                for (int mt = 0; mt < 2; ++mt) {
                    u16x4 pk;
                    #pragma unroll
                    for (int rr = 0; rr < 4; ++rr)
                        pk[rr] = f2bf(fmaxf(a2[f2][mt][rr] + bb2[rr], 0.f) * swv[mt]);
                    *(u16x4*)&H2T[e][(mt*16 + n15) * PH2 + f2*16 + q*4] = pk;
                }
            }
        }

        lbar();                     // all 8 experts' h2 ready (only mid-layer barrier)

        // ===== ACC init (deferred: ACC dead during G1/G2) =====
        acc_init(l);

        // ===== G3: all 8 experts, both row-tiles, cols wv*64..+63 =====
        #pragma unroll
        for (int e = 0; e < ENUM; ++e) {
            u16x8 w3f[4];
            const unsigned short* p3 = w3base + (size_t)(sbase + e) * 8192;
            #pragma unroll
            for (int nt = 0; nt < 4; ++nt)
                w3f[nt] = *(const u16x8*)(p3 + nt * 512);
            u16x8 h0  = *(const u16x8*)&H2T[e][(n15) * PH2 + q*8];
            u16x8 h1v = *(const u16x8*)&H2T[e][(16 + n15) * PH2 + q*8];
            #pragma unroll
            for (int nt = 0; nt < 4; ++nt) {
                ACC[0][nt] = mfma16(h0,  w3f[nt], ACC[0][nt]);
                ACC[1][nt] = mfma16(h1v, w3f[nt], ACC[1][nt]);
            }
        }

        // ===== layer transition =====
        if (l < LNUM - 1) {
            x_write();
            lbar();
            xf_read();
            stage_softmax(l + 1);
            lbar();
        }
    }

    // ================= final store (fp32) =================
    #pragma unroll
    for (int mt = 0; mt < 2; ++mt)
        #pragma unroll
        for (int nt = 0; nt < 4; ++nt)
            #pragma unroll
            for (int rr = 0; rr < 4; ++rr)
                out[(size_t)(b0 + mt*16 + q*4 + rr) * DDIM
                    + wv*64 + nt*16 + n15] = ACC[mt][nt][rr];
}

extern "C" void kernel_launch(void* const* d_in, const int* in_sizes, int n_in,
                              void* d_out, int out_size, void* d_ws, size_t ws_size,
                              hipStream_t stream) {
    const float* src   = (const float*)d_in[0];
    const float* W1    = (const float*)d_in[1];
    const float* b1    = (const float*)d_in[2];
    const float* W2    = (const float*)d_in[3];
    const float* b2    = (const float*)d_in[4];
    const float* W3    = (const float*)d_in[5];
    const float* b3    = (const float*)d_in[6];
    const float* masks = (const float*)d_in[7];
    float* out = (float*)d_out;
    unsigned short* ws = (unsigned short*)d_ws;   // needs 3,407,872 B

    hipLaunchKernelGGL(cvt_w_frag, dim3(832), dim3(256), 0, stream, W1, W2, W3, ws);
    hipLaunchKernelGGL(moe_fused, dim3(BSZ / BT), dim3(NTHR), 0, stream,
                       src, ws, b1, b2, b3, masks, out);
}

// Round 13
// 177.825 us; speedup vs baseline: 1.2847x; 1.0631x over previous
//
#include <hip/hip_runtime.h>
#include <hip/hip_bf16.h>

// Problem constants
#define LNUM 8
#define ENUM 8
#define DDIM 256
#define BSZ  16384
#define H1N  64
#define H2N  32

#define BT   32     // rows per block  (grid 512 -> 2 blocks/CU)
#define NTHR 256    // 4 waves (256-thread shape: compiler allocates ~100 VGPR)

// LDS pitches (u16 elements); odd 16B-granule strides -> conflict-light
#define PX   264    // x tile (D + 8)
#define PH1  72     // h1 tile pitch (H1 + 8)   [row][feat]
#define PH2  40     // h2 tile pitch (H2 + 8)   [row][feat]
#define PSW  9      // softmax weights pitch (floats)

// ws element offsets (u16 elems) for fragment-ordered weights
#define WS1_OFF 0           // 64 steps * 16384 elems
#define WS2_OFF 1048576     // 64 steps * 2048
#define WS3_OFF 1179648     // 64 steps * 8192

typedef float f32x4 __attribute__((ext_vector_type(4)));
typedef unsigned short u16x8 __attribute__((ext_vector_type(8)));
typedef unsigned short u16x4 __attribute__((ext_vector_type(4)));
typedef __bf16 bf16x8 __attribute__((ext_vector_type(8)));

#define Z4 ((f32x4){0.f, 0.f, 0.f, 0.f})

// f32 -> bf16 RTNE via native cast (compiler pairs into v_cvt_pk_bf16_f32).
static __device__ __forceinline__ unsigned short f2bf(float f) {
    __bf16 h = (__bf16)f;
    return __builtin_bit_cast(unsigned short, h);
}

// D[m][n] = sum_k A[m][k]*B[n][k] + C : A supplies m, B supplies n, frags are
// symmetric [idx16][K] -> swapping args transposes the output tile.
static __device__ __forceinline__ f32x4 mfma16(u16x8 a, u16x8 b, f32x4 c) {
    return __builtin_amdgcn_mfma_f32_16x16x32_bf16(
        __builtin_bit_cast(bf16x8, a), __builtin_bit_cast(bf16x8, b), c, 0, 0, 0);
}

// Barrier with lgkmcnt-only drain: LDS producer/consumer ordering preserved,
// in-flight GLOBAL loads are NOT drained (vs __syncthreads' vmcnt(0)).
// Safe: all inter-wave data flows through LDS; no global stores in the loop.
// HW-validated rounds 2/4/5/6/7/8/9/10/11/12.
static __device__ __forceinline__ void lbar() {
    asm volatile("s_waitcnt lgkmcnt(0)" ::: "memory");
    __builtin_amdgcn_s_barrier();
    asm volatile("" ::: "memory");
}

// ---------------------------------------------------------------------------
// Kernel 1: fp32 weights -> bf16 B-fragment layout. Unchanged.
// Fragment: 64 lanes x 8 elems; slot (q*16+r) holds W[n0+r][k0+q*8 .. +7].
// ---------------------------------------------------------------------------
__global__ __launch_bounds__(256) void cvt_w_frag(
    const float* __restrict__ w1, const float* __restrict__ w2,
    const float* __restrict__ w3, unsigned short* __restrict__ ws)
{
    int gid = blockIdx.x * 256 + threadIdx.x;
    const float* src;
    unsigned short* dst;
    if (gid < 131072) {                          // W1: [s][n(64)][k(256)]
        int s = gid >> 11, rem = gid & 2047;
        int n = rem >> 5, kc = rem & 31;
        int nt = n >> 4, r = n & 15, kt = kc >> 2, q = kc & 3;
        src = w1 + (size_t)gid * 8;
        dst = ws + WS1_OFF + (size_t)s * 16384 + nt * 4096 + kt * 512 + (q * 16 + r) * 8;
    } else if (gid < 147456) {                   // W2: [s][n(32)][k(64)]
        int g = gid - 131072;
        int s = g >> 8, rem = g & 255;
        int n = rem >> 3, kc = rem & 7;
        int n2 = n >> 4, r = n & 15, kt = kc >> 2, q = kc & 3;
        src = w2 + (size_t)g * 8;
        dst = ws + WS2_OFF + (size_t)s * 2048 + n2 * 1024 + kt * 512 + (q * 16 + r) * 8;
    } else {                                     // W3: [s][n(256)][k(32)]
        int g = gid - 147456;
        int s = g >> 10, rem = g & 1023;
        int n = rem >> 2, q = rem & 3;
        int nt = n >> 4, r = n & 15;
        src = w3 + (size_t)g * 8;
        dst = ws + WS3_OFF + (size_t)s * 8192 + nt * 512 + (q * 16 + r) * 8;
    }
    float4 a = *(const float4*)src;
    float4 b = *(const float4*)(src + 4);
    u16x8 p;
    p[0] = f2bf(a.x); p[1] = f2bf(a.y); p[2] = f2bf(a.z); p[3] = f2bf(a.w);
    p[4] = f2bf(b.x); p[5] = f2bf(b.y); p[6] = f2bf(b.z); p[7] = f2bf(b.w);
    *(u16x8*)dst = p;
}

// ---------------------------------------------------------------------------
// Kernel 2: fused 8-layer x 8-expert MoE MLP — R8 structure (4 waves, wave wv
// owns experts {wv, wv+4} end-to-end through G1/G2 with a wave-private H1
// transpose; one mid-layer barrier; G3 fans in all 8 experts). Two changes:
//  (a) G1 split-accumulator: batched w1f[8] loads kept VERBATIM (R12 showed
//      per-kt paired loads regress), but even/odd-kt partials give 4
//      independent MFMA chains of length 4 (was 2x8) -> 2x the dependent-
//      latency hiding in the phase holding 128 of 208 MFMAs/wave/layer.
//  (b) Softmax parity double-buffer: next layer's softmax is computed right
//      after the mid-layer barrier (8 rows per wave, lanes 0-7), deleting
//      the second transition barrier -> 2 barriers/layer (was 3).
// ---------------------------------------------------------------------------
__global__ __launch_bounds__(NTHR, 2) void moe_fused(
    const float* __restrict__ src, const unsigned short* __restrict__ Wf,
    const float* __restrict__ b1, const float* __restrict__ b2,
    const float* __restrict__ b3, const float* __restrict__ masks,
    float* __restrict__ out)
{
    __shared__ __align__(16) unsigned short Xlds[BT * PX];        // 16896 B
    __shared__ __align__(16) unsigned short H1W[4][BT * PH1];     // 18432 B wave-private
    __shared__ __align__(16) unsigned short H2T[8][BT * PH2];     // 20480 B per-expert
    __shared__ float SWlds[2][BT * PSW];                          //  2304 B parity dbuf
    // total 58112 B -> 2 blocks/CU (116224 <= 163840)

    const int tid  = threadIdx.x;
    const int lane = tid & 63;
    const int wv   = tid >> 6;      // wave id 0..3: experts {wv, wv+4}; G3 col grp
    const int n15  = lane & 15;
    const int q    = lane >> 4;
    const int b0   = blockIdx.x * BT;

    const unsigned short* w3base = Wf + WS3_OFF + wv * 2048 + lane * 8;

    u16x8 xf[2][8];          // persistent x B-frags (64 VGPR; dead during G3)
    f32x4 ACC[2][4];         // output accumulator (dead during G1/G2)

    // Distributed softmax for layer l into SWlds[p]: each wave's lanes 0-7
    // handle rows wv*8 .. wv*8+7 (32 rows total). Writes are ordered before
    // any reader by the next barrier (G2: transition bar; acc_init: mid bar).
    auto stage_softmax = [&](int l, int p) {
        if (lane < 8) {
            int row = wv * 8 + lane;
            const float* mp = masks + ((size_t)l * BSZ + b0 + row) * ENUM;
            float4 m0 = *(const float4*)mp;
            float4 m1 = *(const float4*)(mp + 4);
            float mv[8] = {m0.x, m0.y, m0.z, m0.w, m1.x, m1.y, m1.z, m1.w};
            float mx = mv[0];
            #pragma unroll
            for (int e = 1; e < 8; ++e) mx = fmaxf(mx, mv[e]);
            float s = 0.f;
            #pragma unroll
            for (int e = 0; e < 8; ++e) { mv[e] = expf(mv[e] - mx); s += mv[e]; }
            float inv = 1.f / s;
            #pragma unroll
            for (int e = 0; e < 8; ++e) SWlds[p][row * PSW + e] = mv[e] * inv;
        }
    };

    // ACC = sum_e softmax_w[row][e] * b3[e][col]  (fp32 VALU, once per layer)
    auto acc_init = [&](int l) {
        const float* b3l = b3 + (size_t)l * ENUM * DDIM;
        const int p = l & 1;
        #pragma unroll
        for (int mt = 0; mt < 2; ++mt)
            #pragma unroll
            for (int nt = 0; nt < 4; ++nt) ACC[mt][nt] = Z4;
        #pragma unroll 2
        for (int e2 = 0; e2 < ENUM; ++e2) {
            float swv[2][4];
            #pragma unroll
            for (int mt = 0; mt < 2; ++mt)
                #pragma unroll
                for (int rr = 0; rr < 4; ++rr)
                    swv[mt][rr] = SWlds[p][(mt*16 + q*4 + rr) * PSW + e2];
            #pragma unroll
            for (int nt = 0; nt < 4; ++nt) {
                float bv = b3l[e2 * DDIM + wv*64 + nt*16 + n15];
                #pragma unroll
                for (int mt = 0; mt < 2; ++mt)
                    #pragma unroll
                    for (int rr = 0; rr < 4; ++rr)
                        ACC[mt][nt][rr] += swv[mt][rr] * bv;
            }
        }
    };

    auto xf_read = [&]() {
        #pragma unroll
        for (int mt = 0; mt < 2; ++mt)
            #pragma unroll
            for (int kt = 0; kt < 8; ++kt)
                xf[mt][kt] = *(const u16x8*)
                    &Xlds[(mt*16 + n15) * PX + q*8 + kt*32];
    };
    auto x_write = [&]() {
        #pragma unroll
        for (int mt = 0; mt < 2; ++mt)
            #pragma unroll
            for (int nt = 0; nt < 4; ++nt)
                #pragma unroll
                for (int rr = 0; rr < 4; ++rr)
                    Xlds[(mt*16 + q*4 + rr) * PX + wv*64 + nt*16 + n15] =
                        f2bf(ACC[mt][nt][rr]);
    };

    // ================= prologue =================
    #pragma unroll
    for (int i = 0; i < 4; ++i) {                // stage layer-0 x (bf16)
        int o = (i * NTHR + tid) * 8;
        int r = o >> 8, c = o & 255;
        const float* p = src + (size_t)(b0 + r) * DDIM + c;
        float4 f0 = *(const float4*)(p);
        float4 f1 = *(const float4*)(p + 4);
        u16x8 pk;
        pk[0] = f2bf(f0.x); pk[1] = f2bf(f0.y); pk[2] = f2bf(f0.z); pk[3] = f2bf(f0.w);
        pk[4] = f2bf(f1.x); pk[5] = f2bf(f1.y); pk[6] = f2bf(f1.z); pk[7] = f2bf(f1.w);
        *(u16x8*)&Xlds[r * PX + c] = pk;
    }
    stage_softmax(0, 0);
    __syncthreads();
    xf_read();

    // ================= layer loop =================
    #pragma unroll 1
    for (int l = 0; l < LNUM; ++l) {
        const int sbase = l * ENUM;

        // ===== G1+G2 for this wave's two experts (barrier-free) =====
        #pragma unroll
        for (int pe = 0; pe < 2; ++pe) {
            const int e = wv + pe * 4;
            const int s = sbase + e;

            // ---- G1: h1 = relu(x @ W1^T + b1), 4 feat-tiles ----
            // Batched w1f[8] loads (R8 schedule); even/odd-kt split gives 4
            // independent MFMA chains (length 4) vs R8's 2 chains (length 8).
            // lane -> feats ft*16+q*4+rr, rows mt*16+n15 (transposed MFMA)
            #pragma unroll
            for (int ft = 0; ft < 4; ++ft) {
                u16x8 w1f[8];
                const unsigned short* p1 =
                    Wf + WS1_OFF + (size_t)s * 16384 + ft * 4096 + lane * 8;
                #pragma unroll
                for (int kt = 0; kt < 8; ++kt)
                    w1f[kt] = *(const u16x8*)(p1 + kt * 512);
                f32x4 a1e[2] = {Z4, Z4}, a1o[2] = {Z4, Z4};
                #pragma unroll
                for (int kt = 0; kt < 8; kt += 2) {
                    a1e[0] = mfma16(w1f[kt],   xf[0][kt],   a1e[0]);
                    a1e[1] = mfma16(w1f[kt],   xf[1][kt],   a1e[1]);
                    a1o[0] = mfma16(w1f[kt+1], xf[0][kt+1], a1o[0]);
                    a1o[1] = mfma16(w1f[kt+1], xf[1][kt+1], a1o[1]);
                }
                const float4 bb1 = *(const float4*)(b1 + s * 64 + ft * 16 + q * 4);
                #pragma unroll
                for (int mt = 0; mt < 2; ++mt) {
                    u16x4 pk;
                    #pragma unroll
                    for (int rr = 0; rr < 4; ++rr)
                        pk[rr] = f2bf(fmaxf(a1e[mt][rr] + a1o[mt][rr] + bb1[rr], 0.f));
                    *(u16x4*)&H1W[wv][(mt*16 + n15) * PH1 + ft*16 + q*4] = pk;
                }
            }

            // ---- G2: h2 = relu(h1 @ W2^T + b2) * sw[e] ----
            // intra-wave H1W write->read: compiler-ordered lgkmcnt, no barrier
            {
                u16x8 w2f[2][2];
                const unsigned short* p2 =
                    Wf + WS2_OFF + (size_t)s * 2048 + lane * 8;
                #pragma unroll
                for (int f2 = 0; f2 < 2; ++f2)
                    #pragma unroll
                    for (int kt = 0; kt < 2; ++kt)
                        w2f[f2][kt] = *(const u16x8*)(p2 + f2*1024 + kt*512);
                u16x8 h1f[2][2];
                #pragma unroll
                for (int mt = 0; mt < 2; ++mt)
                    #pragma unroll
                    for (int kt = 0; kt < 2; ++kt)
                        h1f[mt][kt] = *(const u16x8*)
                            &H1W[wv][(mt*16 + n15) * PH1 + q*8 + kt*32];
                f32x4 a2[2][2] = {{Z4, Z4}, {Z4, Z4}};
                #pragma unroll
                for (int f2 = 0; f2 < 2; ++f2)
                    #pragma unroll
                    for (int mt = 0; mt < 2; ++mt)
                        #pragma unroll
                        for (int kt = 0; kt < 2; ++kt)
                            a2[f2][mt] = mfma16(w2f[f2][kt], h1f[mt][kt], a2[f2][mt]);
                float swv[2];
                #pragma unroll
                for (int mt = 0; mt < 2; ++mt)
                    swv[mt] = SWlds[l & 1][(mt*16 + n15) * PSW + e];
                #pragma unroll
                for (int f2 = 0; f2 < 2; ++f2) {
                    const float4 bb2 = *(const float4*)(b2 + s * 32 + f2 * 16 + q * 4);
                    #pragma unroll
                    for (int mt = 0; mt < 2; ++mt) {
                        u16x4 pk;
                        #pragma unroll
                        for (int rr = 0; rr < 4; ++rr)
                            pk[rr] = f2bf(fmaxf(a2[f2][mt][rr] + bb2[rr], 0.f) * swv[mt]);
                        *(u16x4*)&H2T[e][(mt*16 + n15) * PH2 + f2*16 + q*4] = pk;
                    }
                }
            }
        }

        lbar();                     // all 8 experts' h2 ready (only mid-layer barrier)

        // ===== next layer's softmax into the other parity buffer =====
        // Readers (G2(l+1), acc_init(l+1)) are >=1 barrier after this write;
        // stale readers of this parity (acc_init(l-1)) were >=1 barrier before.
        if (l < LNUM - 1) stage_softmax(l + 1, (l + 1) & 1);

        // ===== ACC init (deferred: ACC dead during G1/G2) =====
        acc_init(l);

        // ===== G3: all 8 experts, both row-tiles, cols wv*64..+63 =====
        #pragma unroll
        for (int e = 0; e < ENUM; ++e) {
            u16x8 w3f[4];
            const unsigned short* p3 = w3base + (size_t)(sbase + e) * 8192;
            #pragma unroll
            for (int nt = 0; nt < 4; ++nt)
                w3f[nt] = *(const u16x8*)(p3 + nt * 512);
            u16x8 h0  = *(const u16x8*)&H2T[e][(n15) * PH2 + q*8];
            u16x8 h1v = *(const u16x8*)&H2T[e][(16 + n15) * PH2 + q*8];
            #pragma unroll
            for (int nt = 0; nt < 4; ++nt) {
                ACC[0][nt] = mfma16(h0,  w3f[nt], ACC[0][nt]);
                ACC[1][nt] = mfma16(h1v, w3f[nt], ACC[1][nt]);
            }
        }

        // ===== layer transition (single barrier: x_write -> bar -> xf_read) =====
        if (l < LNUM - 1) {
            x_write();
            lbar();
            xf_read();
        }
    }

    // ================= final store (fp32) =================
    #pragma unroll
    for (int mt = 0; mt < 2; ++mt)
        #pragma unroll
        for (int nt = 0; nt < 4; ++nt)
            #pragma unroll
            for (int rr = 0; rr < 4; ++rr)
                out[(size_t)(b0 + mt*16 + q*4 + rr) * DDIM
                    + wv*64 + nt*16 + n15] = ACC[mt][nt][rr];
}

extern "C" void kernel_launch(void* const* d_in, const int* in_sizes, int n_in,
                              void* d_out, int out_size, void* d_ws, size_t ws_size,
                              hipStream_t stream) {
    const float* src   = (const float*)d_in[0];
    const float* W1    = (const float*)d_in[1];
    const float* b1    = (const float*)d_in[2];
    const float* W2    = (const float*)d_in[3];
    const float* b2    = (const float*)d_in[4];
    const float* W3    = (const float*)d_in[5];
    const float* b3    = (const float*)d_in[6];
    const float* masks = (const float*)d_in[7];
    float* out = (float*)d_out;
    unsigned short* ws = (unsigned short*)d_ws;   // needs 3,407,872 B

    hipLaunchKernelGGL(cvt_w_frag, dim3(832), dim3(256), 0, stream, W1, W2, W3, ws);
    hipLaunchKernelGGL(moe_fused, dim3(BSZ / BT), dim3(NTHR), 0, stream,
                       src, ws, b1, b2, b3, masks, out);
}

// Round 14
// 166.687 us; speedup vs baseline: 1.3706x; 1.0668x over previous
//
#include <hip/hip_runtime.h>
#include <hip/hip_bf16.h>

// Problem constants
#define LNUM 8
#define ENUM 8
#define DDIM 256
#define BSZ  16384
#define H1N  64
#define H2N  32

#define BT   32     // rows per block  (grid 512 -> 2 blocks/CU)
#define NTHR 256    // 4 waves (256-thread shape compiles to ~100-120 VGPR)

// LDS pitches (u16 elements); odd 16B-granule strides -> conflict-light
#define PX   264    // x tile (D + 8)
#define PH1  72     // h1 tile pitch (H1 + 8)   [row][feat]
#define PH2  40     // h2 tile pitch (H2 + 8)   [row][feat]
#define PSW  9      // softmax weights pitch (floats)

// ws element offsets (u16 elems) for fragment-ordered weights
#define WS1_OFF 0           // 64 steps * 16384 elems
#define WS2_OFF 1048576     // 64 steps * 2048
#define WS3_OFF 1179648     // 64 steps * 8192

typedef float f32x4 __attribute__((ext_vector_type(4)));
typedef unsigned short u16x8 __attribute__((ext_vector_type(8)));
typedef unsigned short u16x4 __attribute__((ext_vector_type(4)));
typedef __bf16 bf16x8 __attribute__((ext_vector_type(8)));

#define Z4 ((f32x4){0.f, 0.f, 0.f, 0.f})

// f32 -> bf16 RTNE via native cast (compiler pairs into v_cvt_pk_bf16_f32).
static __device__ __forceinline__ unsigned short f2bf(float f) {
    __bf16 h = (__bf16)f;
    return __builtin_bit_cast(unsigned short, h);
}

// D[m][n] = sum_k A[m][k]*B[n][k] + C : A supplies m, B supplies n, frags are
// symmetric [idx16][K] -> swapping args transposes the output tile.
static __device__ __forceinline__ f32x4 mfma16(u16x8 a, u16x8 b, f32x4 c) {
    return __builtin_amdgcn_mfma_f32_16x16x32_bf16(
        __builtin_bit_cast(bf16x8, a), __builtin_bit_cast(bf16x8, b), c, 0, 0, 0);
}

// Barrier with lgkmcnt-only drain: LDS producer/consumer ordering preserved,
// in-flight GLOBAL loads are NOT drained (vs __syncthreads' vmcnt(0)).
// Safe: all inter-wave data flows through LDS; no global stores in the loop.
// HW-validated rounds 2/4/5/6/7/8/12/13.
static __device__ __forceinline__ void lbar() {
    asm volatile("s_waitcnt lgkmcnt(0)" ::: "memory");
    __builtin_amdgcn_s_barrier();
    asm volatile("" ::: "memory");
}

// ---------------------------------------------------------------------------
// Kernel 1: fp32 weights -> bf16 B-fragment layout. Unchanged.
// Fragment: 64 lanes x 8 elems; slot (q*16+r) holds W[n0+r][k0+q*8 .. +7].
// ---------------------------------------------------------------------------
__global__ __launch_bounds__(256) void cvt_w_frag(
    const float* __restrict__ w1, const float* __restrict__ w2,
    const float* __restrict__ w3, unsigned short* __restrict__ ws)
{
    int gid = blockIdx.x * 256 + threadIdx.x;
    const float* src;
    unsigned short* dst;
    if (gid < 131072) {                          // W1: [s][n(64)][k(256)]
        int s = gid >> 11, rem = gid & 2047;
        int n = rem >> 5, kc = rem & 31;
        int nt = n >> 4, r = n & 15, kt = kc >> 2, q = kc & 3;
        src = w1 + (size_t)gid * 8;
        dst = ws + WS1_OFF + (size_t)s * 16384 + nt * 4096 + kt * 512 + (q * 16 + r) * 8;
    } else if (gid < 147456) {                   // W2: [s][n(32)][k(64)]
        int g = gid - 131072;
        int s = g >> 8, rem = g & 255;
        int n = rem >> 3, kc = rem & 7;
        int n2 = n >> 4, r = n & 15, kt = kc >> 2, q = kc & 3;
        src = w2 + (size_t)g * 8;
        dst = ws + WS2_OFF + (size_t)s * 2048 + n2 * 1024 + kt * 512 + (q * 16 + r) * 8;
    } else {                                     // W3: [s][n(256)][k(32)]
        int g = gid - 147456;
        int s = g >> 10, rem = g & 1023;
        int n = rem >> 2, q = rem & 3;
        int nt = n >> 4, r = n & 15;
        src = w3 + (size_t)g * 8;
        dst = ws + WS3_OFF + (size_t)s * 8192 + nt * 512 + (q * 16 + r) * 8;
    }
    float4 a = *(const float4*)src;
    float4 b = *(const float4*)(src + 4);
    u16x8 p;
    p[0] = f2bf(a.x); p[1] = f2bf(a.y); p[2] = f2bf(a.z); p[3] = f2bf(a.w);
    p[4] = f2bf(b.x); p[5] = f2bf(b.y); p[6] = f2bf(b.z); p[7] = f2bf(b.w);
    *(u16x8*)dst = p;
}

// ---------------------------------------------------------------------------
// Kernel 2: fused 8-layer x 8-expert MoE MLP — R8 structure (4 waves, wave wv
// owns experts {wv, wv+4} end-to-end through G1/G2, wave-private H1
// transpose, G3 fans in all 8 experts) with three refinements:
//  (a) W3 rotation: e=0's W3 frags preloaded BEFORE the mid-layer barrier
//      (xf is dead there -> lowest-pressure crossing, ~16 regs), and each
//      e+1's loads issue before e's MFMAs -> every G3 load covered by >=8
//      MFMAs + acc_init VALU instead of exposed per-expert.
//  (b) Softmax parity double-buffer, computed post-mid-barrier ->
//      2 barriers/layer (was 3). (R13's clean half; split-acc dropped.)
//  (c) s_setprio(1) around G1/G3 MFMA clusters (2 independent blocks/CU =
//      phase-diverse waves, the regime where setprio measured +4-7%).
// ---------------------------------------------------------------------------
__global__ __launch_bounds__(NTHR, 2) void moe_fused(
    const float* __restrict__ src, const unsigned short* __restrict__ Wf,
    const float* __restrict__ b1, const float* __restrict__ b2,
    const float* __restrict__ b3, const float* __restrict__ masks,
    float* __restrict__ out)
{
    __shared__ __align__(16) unsigned short Xlds[BT * PX];        // 16896 B
    __shared__ __align__(16) unsigned short H1W[4][BT * PH1];     // 18432 B wave-private
    __shared__ __align__(16) unsigned short H2T[8][BT * PH2];     // 20480 B per-expert
    __shared__ float SWlds[2][BT * PSW];                          //  2304 B parity dbuf
    // total 58112 B -> 2 blocks/CU (116224 <= 163840)

    const int tid  = threadIdx.x;
    const int lane = tid & 63;
    const int wv   = tid >> 6;      // wave id 0..3: experts {wv, wv+4}; G3 col grp
    const int n15  = lane & 15;
    const int q    = lane >> 4;
    const int b0   = blockIdx.x * BT;

    const unsigned short* w3base = Wf + WS3_OFF + wv * 2048 + lane * 8;

    u16x8 xf[2][8];          // persistent x B-frags (dead during G3 + at mid-bar)
    f32x4 ACC[2][4];         // output accumulator (dead during G1/G2)

    // Distributed softmax for layer l into SWlds[p]: each wave's lanes 0-7
    // handle rows wv*8 .. wv*8+7. Readers (G2(l), acc_init(l)) are >=1
    // barrier after the write; stale readers of parity p are >=2 before.
    auto stage_softmax = [&](int l, int p) {
        if (lane < 8) {
            int row = wv * 8 + lane;
            const float* mp = masks + ((size_t)l * BSZ + b0 + row) * ENUM;
            float4 m0 = *(const float4*)mp;
            float4 m1 = *(const float4*)(mp + 4);
            float mv[8] = {m0.x, m0.y, m0.z, m0.w, m1.x, m1.y, m1.z, m1.w};
            float mx = mv[0];
            #pragma unroll
            for (int e = 1; e < 8; ++e) mx = fmaxf(mx, mv[e]);
            float s = 0.f;
            #pragma unroll
            for (int e = 0; e < 8; ++e) { mv[e] = expf(mv[e] - mx); s += mv[e]; }
            float inv = 1.f / s;
            #pragma unroll
            for (int e = 0; e < 8; ++e) SWlds[p][row * PSW + e] = mv[e] * inv;
        }
    };

    // ACC = sum_e softmax_w[row][e] * b3[e][col]  (fp32 VALU, once per layer)
    auto acc_init = [&](int l) {
        const float* b3l = b3 + (size_t)l * ENUM * DDIM;
        const int p = l & 1;
        #pragma unroll
        for (int mt = 0; mt < 2; ++mt)
            #pragma unroll
            for (int nt = 0; nt < 4; ++nt) ACC[mt][nt] = Z4;
        #pragma unroll 2
        for (int e2 = 0; e2 < ENUM; ++e2) {
            float swv[2][4];
            #pragma unroll
            for (int mt = 0; mt < 2; ++mt)
                #pragma unroll
                for (int rr = 0; rr < 4; ++rr)
                    swv[mt][rr] = SWlds[p][(mt*16 + q*4 + rr) * PSW + e2];
            #pragma unroll
            for (int nt = 0; nt < 4; ++nt) {
                float bv = b3l[e2 * DDIM + wv*64 + nt*16 + n15];
                #pragma unroll
                for (int mt = 0; mt < 2; ++mt)
                    #pragma unroll
                    for (int rr = 0; rr < 4; ++rr)
                        ACC[mt][nt][rr] += swv[mt][rr] * bv;
            }
        }
    };

    auto xf_read = [&]() {
        #pragma unroll
        for (int mt = 0; mt < 2; ++mt)
            #pragma unroll
            for (int kt = 0; kt < 8; ++kt)
                xf[mt][kt] = *(const u16x8*)
                    &Xlds[(mt*16 + n15) * PX + q*8 + kt*32];
    };
    auto x_write = [&]() {
        #pragma unroll
        for (int mt = 0; mt < 2; ++mt)
            #pragma unroll
            for (int nt = 0; nt < 4; ++nt)
                #pragma unroll
                for (int rr = 0; rr < 4; ++rr)
                    Xlds[(mt*16 + q*4 + rr) * PX + wv*64 + nt*16 + n15] =
                        f2bf(ACC[mt][nt][rr]);
    };

    // ================= prologue =================
    #pragma unroll
    for (int i = 0; i < 4; ++i) {                // stage layer-0 x (bf16)
        int o = (i * NTHR + tid) * 8;
        int r = o >> 8, c = o & 255;
        const float* p = src + (size_t)(b0 + r) * DDIM + c;
        float4 f0 = *(const float4*)(p);
        float4 f1 = *(const float4*)(p + 4);
        u16x8 pk;
        pk[0] = f2bf(f0.x); pk[1] = f2bf(f0.y); pk[2] = f2bf(f0.z); pk[3] = f2bf(f0.w);
        pk[4] = f2bf(f1.x); pk[5] = f2bf(f1.y); pk[6] = f2bf(f1.z); pk[7] = f2bf(f1.w);
        *(u16x8*)&Xlds[r * PX + c] = pk;
    }
    stage_softmax(0, 0);
    __syncthreads();
    xf_read();

    // ================= layer loop =================
    #pragma unroll 1
    for (int l = 0; l < LNUM; ++l) {
        const int sbase = l * ENUM;

        // ===== G1+G2 for this wave's two experts (barrier-free) =====
        #pragma unroll
        for (int pe = 0; pe < 2; ++pe) {
            const int e = wv + pe * 4;
            const int s = sbase + e;

            // ---- G1: h1 = relu(x @ W1^T + b1), 4 feat-tiles ----
            // Batched w1f[8] loads (R8 schedule, best measured).
            // lane -> feats ft*16+q*4+rr, rows mt*16+n15 (transposed MFMA)
            #pragma unroll
            for (int ft = 0; ft < 4; ++ft) {
                u16x8 w1f[8];
                const unsigned short* p1 =
                    Wf + WS1_OFF + (size_t)s * 16384 + ft * 4096 + lane * 8;
                #pragma unroll
                for (int kt = 0; kt < 8; ++kt)
                    w1f[kt] = *(const u16x8*)(p1 + kt * 512);
                f32x4 a1[2] = {Z4, Z4};
                __builtin_amdgcn_s_setprio(1);
                #pragma unroll
                for (int kt = 0; kt < 8; ++kt) {
                    a1[0] = mfma16(w1f[kt], xf[0][kt], a1[0]);
                    a1[1] = mfma16(w1f[kt], xf[1][kt], a1[1]);
                }
                __builtin_amdgcn_s_setprio(0);
                const float4 bb1 = *(const float4*)(b1 + s * 64 + ft * 16 + q * 4);
                #pragma unroll
                for (int mt = 0; mt < 2; ++mt) {
                    u16x4 pk;
                    #pragma unroll
                    for (int rr = 0; rr < 4; ++rr)
                        pk[rr] = f2bf(fmaxf(a1[mt][rr] + bb1[rr], 0.f));
                    *(u16x4*)&H1W[wv][(mt*16 + n15) * PH1 + ft*16 + q*4] = pk;
                }
            }

            // ---- G2: h2 = relu(h1 @ W2^T + b2) * sw[e] ----
            // intra-wave H1W write->read: compiler-ordered lgkmcnt, no barrier
            {
                u16x8 w2f[2][2];
                const unsigned short* p2 =
                    Wf + WS2_OFF + (size_t)s * 2048 + lane * 8;
                #pragma unroll
                for (int f2 = 0; f2 < 2; ++f2)
                    #pragma unroll
                    for (int kt = 0; kt < 2; ++kt)
                        w2f[f2][kt] = *(const u16x8*)(p2 + f2*1024 + kt*512);
                u16x8 h1f[2][2];
                #pragma unroll
                for (int mt = 0; mt < 2; ++mt)
                    #pragma unroll
                    for (int kt = 0; kt < 2; ++kt)
                        h1f[mt][kt] = *(const u16x8*)
                            &H1W[wv][(mt*16 + n15) * PH1 + q*8 + kt*32];
                f32x4 a2[2][2] = {{Z4, Z4}, {Z4, Z4}};
                #pragma unroll
                for (int f2 = 0; f2 < 2; ++f2)
                    #pragma unroll
                    for (int mt = 0; mt < 2; ++mt)
                        #pragma unroll
                        for (int kt = 0; kt < 2; ++kt)
                            a2[f2][mt] = mfma16(w2f[f2][kt], h1f[mt][kt], a2[f2][mt]);
                float swv[2];
                #pragma unroll
                for (int mt = 0; mt < 2; ++mt)
                    swv[mt] = SWlds[l & 1][(mt*16 + n15) * PSW + e];
                #pragma unroll
                for (int f2 = 0; f2 < 2; ++f2) {
                    const float4 bb2 = *(const float4*)(b2 + s * 32 + f2 * 16 + q * 4);
                    #pragma unroll
                    for (int mt = 0; mt < 2; ++mt) {
                        u16x4 pk;
                        #pragma unroll
                        for (int rr = 0; rr < 4; ++rr)
                            pk[rr] = f2bf(fmaxf(a2[f2][mt][rr] + bb2[rr], 0.f) * swv[mt]);
                        *(u16x4*)&H2T[e][(mt*16 + n15) * PH2 + f2*16 + q*4] = pk;
                    }
                }
            }
        }

        // ===== W3 prefetch for e=0: crosses the mid-layer barrier at the
        //       kernel's lowest-pressure point (xf dead here, ~16 regs) =====
        u16x8 w3a[4], w3b[4];
        {
            const unsigned short* p3 = w3base + (size_t)sbase * 8192;
            #pragma unroll
            for (int nt = 0; nt < 4; ++nt)
                w3a[nt] = *(const u16x8*)(p3 + nt * 512);
        }

        lbar();                     // mid-layer barrier; W3(e=0) stays in flight

        // ===== next layer's softmax into the other parity buffer =====
        if (l < LNUM - 1) stage_softmax(l + 1, (l + 1) & 1);

        // ===== ACC init (VALU; covers W3(e=0) flight) =====
        acc_init(l);

        // ===== G3: all 8 experts, rotated W3 (ping-pong, full unroll) =====
        #pragma unroll
        for (int e = 0; e < ENUM; ++e) {
            // issue NEXT expert's W3 loads before this expert's MFMAs
            if (e < ENUM - 1) {
                const unsigned short* p3 = w3base + (size_t)(sbase + e + 1) * 8192;
                u16x8* nxt = (e & 1) ? w3a : w3b;
                #pragma unroll
                for (int nt = 0; nt < 4; ++nt)
                    nxt[nt] = *(const u16x8*)(p3 + nt * 512);
            }
            const u16x8* cur = (e & 1) ? w3b : w3a;
            u16x8 h0  = *(const u16x8*)&H2T[e][(n15) * PH2 + q*8];
            u16x8 h1v = *(const u16x8*)&H2T[e][(16 + n15) * PH2 + q*8];
            __builtin_amdgcn_s_setprio(1);
            #pragma unroll
            for (int nt = 0; nt < 4; ++nt) {
                ACC[0][nt] = mfma16(h0,  cur[nt], ACC[0][nt]);
                ACC[1][nt] = mfma16(h1v, cur[nt], ACC[1][nt]);
            }
            __builtin_amdgcn_s_setprio(0);
        }

        // ===== layer transition (single barrier) =====
        if (l < LNUM - 1) {
            x_write();
            lbar();
            xf_read();
        }
    }

    // ================= final store (fp32) =================
    #pragma unroll
    for (int mt = 0; mt < 2; ++mt)
        #pragma unroll
        for (int nt = 0; nt < 4; ++nt)
            #pragma unroll
            for (int rr = 0; rr < 4; ++rr)
                out[(size_t)(b0 + mt*16 + q*4 + rr) * DDIM
                    + wv*64 + nt*16 + n15] = ACC[mt][nt][rr];
}

extern "C" void kernel_launch(void* const* d_in, const int* in_sizes, int n_in,
                              void* d_out, int out_size, void* d_ws, size_t ws_size,
                              hipStream_t stream) {
    const float* src   = (const float*)d_in[0];
    const float* W1    = (const float*)d_in[1];
    const float* b1    = (const float*)d_in[2];
    const float* W2    = (const float*)d_in[3];
    const float* b2    = (const float*)d_in[4];
    const float* W3    = (const float*)d_in[5];
    const float* b3    = (const float*)d_in[6];
    const float* masks = (const float*)d_in[7];
    float* out = (float*)d_out;
    unsigned short* ws = (unsigned short*)d_ws;   // needs 3,407,872 B

    hipLaunchKernelGGL(cvt_w_frag, dim3(832), dim3(256), 0, stream, W1, W2, W3, ws);
    hipLaunchKernelGGL(moe_fused, dim3(BSZ / BT), dim3(NTHR), 0, stream,
                       src, ws, b1, b2, b3, masks, out);
}